// Round 1
// baseline (774.069 us; speedup 1.0000x reference)
//
#include <hip/hip_runtime.h>
#include <math.h>

typedef float f4 __attribute__((ext_vector_type(4)));
typedef float f2 __attribute__((ext_vector_type(2)));

#define N_NODES 10000
#define N_EDGES 160000

// ---- workspace layout (units: 4-byte words) ----
#define OFF_DEN     0          // 80000 floats (N*8) softmax denominators   [zeroed]
#define OFF_SUMS    80000      // 768: bnc s/sq | bn1 s/sq | bn2 s/sq       [zeroed]
#define OFF_DEG     80768      // 10000 int degrees                         [zeroed]
#define ZERO_WORDS  90768
#define OFF_ROWPTR  90768      // 10001 int
#define OFF_CURSOR  100772     // 10000 int
#define OFF_ELIST   110772     // 160000 int
#define OFF_SS      270772     // 768: bnc scale/shift | bn1 | bn2
#define OFF_QKV     271544     // 3,840,000 f32 (N x 384)
#define OFF_ESC     4111544    // 1,280,000 f32 (E x 8) exp(score)
#define OFF_HRES    5391544    // 1,280,000 f32 (N x 128)
#define OFF_Y       6671544    // 1,280,000 f32 (N x 128) pre-BN2
#define OFF_MID     7951544    // 2,560,000 f32 (N x 256) ffn mid
#define OFF_CBF     10511544   // 10,240,000 words: c as bf16x2 (E x 128)
// total ~83 MB

__device__ __forceinline__ unsigned short f2bf(float f) {
  unsigned int u = __float_as_uint(f);
  u = (u + 0x7fffu + ((u >> 16) & 1u)) >> 16;
  return (unsigned short)u;
}
__device__ __forceinline__ float bfl(unsigned int p) { return __uint_as_float(p << 16); }
__device__ __forceinline__ float bfh(unsigned int p) { return __uint_as_float(p & 0xffff0000u); }

// B-chunk stage: w row-major [rows][rowstride], stage 64 rows (cols of output)
// transposed into wT[128][64]. Global reads are 16B strided (weights are L2-hot);
// LDS writes are conflict-free (consecutive lanes -> consecutive cols).
__device__ __forceinline__ void stage_w128(const float* __restrict__ w, int rowbase,
                                           int rowstride, int koff,
                                           float (*wT)[64], int tid) {
  for (int i = tid; i < 2048; i += 256) {
    int col = i & 63, k4 = i >> 6;
    f4 v = *(const f4*)&w[(rowbase + col) * rowstride + koff + k4 * 4];
    wT[k4 * 4 + 0][col] = v[0];
    wT[k4 * 4 + 1][col] = v[1];
    wT[k4 * 4 + 2][col] = v[2];
    wT[k4 * 4 + 3][col] = v[3];
  }
}

// 64x64 tile GEMM step, K=128: A[row][k] (ld 132, pad kills conflicts),
// B^T[k][col]; 256 threads as 16x16, each 4 rows x 4 cols.
__device__ __forceinline__ void mm64(const float (*aS)[132], const float (*wT)[64],
                                     int tr, int tc, f4 acc[4]) {
#pragma unroll 4
  for (int k = 0; k < 128; k += 4) {
    f4 a0 = *(const f4*)&aS[tr * 4 + 0][k];
    f4 a1 = *(const f4*)&aS[tr * 4 + 1][k];
    f4 a2 = *(const f4*)&aS[tr * 4 + 2][k];
    f4 a3 = *(const f4*)&aS[tr * 4 + 3][k];
#pragma unroll
    for (int kk = 0; kk < 4; ++kk) {
      f4 b = *(const f4*)&wT[k + kk][tc * 4];
      acc[0] += a0[kk] * b;
      acc[1] += a1[kk] * b;
      acc[2] += a2[kk] * b;
      acc[3] += a3[kk] * b;
    }
  }
}

// ---------------- qkv = x @ qkv_w.T + qkv_b ----------------
__global__ __launch_bounds__(256) void k_qkv(const float* __restrict__ x,
                                             const float* __restrict__ w,
                                             const float* __restrict__ b,
                                             float* __restrict__ out) {
  __shared__ float aS[64][132];
  __shared__ float wT[128][64];
  const int tid = threadIdx.x;
  const int r0 = blockIdx.x * 64;
  for (int i = tid; i < 2048; i += 256) {
    int row = i >> 5, kq = i & 31;
    int gr = r0 + row; if (gr > N_NODES - 1) gr = N_NODES - 1;
    *(f4*)&aS[row][kq * 4] = *(const f4*)&x[gr * 128 + kq * 4];
  }
  const int tr = tid >> 4, tc = tid & 15;
#pragma unroll 1
  for (int ch = 0; ch < 6; ++ch) {
    __syncthreads();
    stage_w128(w, ch * 64, 128, 0, wT, tid);
    __syncthreads();
    f4 acc[4] = {};
    mm64(aS, wT, tr, tc, acc);
    f4 bias = *(const f4*)&b[ch * 64 + tc * 4];
#pragma unroll
    for (int r = 0; r < 4; ++r) {
      int gr = r0 + tr * 4 + r;
      if (gr < N_NODES) {
        f4 o = acc[r] + bias;
        *(f4*)&out[gr * 384 + ch * 64 + tc * 4] = o;
      }
    }
  }
}

// ---------------- edge kernel A: Eh, c, score ----------------
// Per 64-edge tile: Eh = conn@w1.T+b1 (Ew|Eb), c = relu(sign*sqrt((Q[dst]+K[src])*Ew)+Eb),
// c -> bf16 buffer; per-head score -> exp(clip) -> escore, atomic den[dst,h].
__global__ __launch_bounds__(256) void k_edgeA(
    const float* __restrict__ conn, const int* __restrict__ ei,
    const float* __restrict__ qkv, const float* __restrict__ w1,
    const float* __restrict__ b1, const float* __restrict__ wsc_g,
    unsigned int* __restrict__ c_out, float* __restrict__ escore,
    float* __restrict__ den) {
  __shared__ float aS[64][132];
  __shared__ float wT[128][64];
  __shared__ float scoreAcc[64][8];
  __shared__ float wsc[16][8];
  const int tid = threadIdx.x;
  const int e0 = blockIdx.x * 64;
  for (int i = tid; i < 2048; i += 256) {
    int row = i >> 5, kq = i & 31;
    *(f4*)&aS[row][kq * 4] = *(const f4*)&conn[(e0 + row) * 128 + kq * 4];
  }
  if (tid < 128) wsc[tid >> 3][tid & 7] = wsc_g[tid];
  const int tr = tid >> 4, tc = tid & 15;
  int dstL[4], srcL[4];
#pragma unroll
  for (int r = 0; r < 4; ++r) {
    dstL[r] = ei[e0 + tr * 4 + r];
    srcL[r] = ei[N_EDGES + e0 + tr * 4 + r];
  }
  __syncthreads();
#pragma unroll 1
  for (int j = 0; j < 2; ++j) {
    f4 accW[4] = {};
    f4 accB[4] = {};
    stage_w128(w1, j * 64, 128, 0, wT, tid);        // Ew rows
    __syncthreads();
    mm64(aS, wT, tr, tc, accW);
    __syncthreads();
    stage_w128(w1, 128 + j * 64, 128, 0, wT, tid);  // Eb rows
    __syncthreads();
    mm64(aS, wT, tr, tc, accB);
    __syncthreads();
    const int cg0 = j * 64 + tc * 4;
    const int head = cg0 >> 4, dl = cg0 & 15;
    f4 bw = *(const f4*)&b1[cg0];
    f4 bb = *(const f4*)&b1[128 + cg0];
#pragma unroll
    for (int r = 0; r < 4; ++r) {
      f4 q = *(const f4*)&qkv[dstL[r] * 384 + cg0];
      f4 kk = *(const f4*)&qkv[srcL[r] * 384 + 128 + cg0];
      f4 ew = accW[r] + bw;
      f4 eb = accB[r] + bb;
      f4 cv;
#pragma unroll
      for (int cq = 0; cq < 4; ++cq) {
        float z = (q[cq] + kk[cq]) * ew[cq];
        float s = copysignf(sqrtf(fabsf(z)), z) + eb[cq];
        cv[cq] = fmaxf(s, 0.f);
      }
      float sp = cv[0] * wsc[dl + 0][head] + cv[1] * wsc[dl + 1][head] +
                 cv[2] * wsc[dl + 2][head] + cv[3] * wsc[dl + 3][head];
      sp += __shfl_xor(sp, 1);
      sp += __shfl_xor(sp, 2);
      if ((tc & 3) == 0) scoreAcc[tr * 4 + r][head] = sp;
      unsigned int p0 = (unsigned int)f2bf(cv[0]) | ((unsigned int)f2bf(cv[1]) << 16);
      unsigned int p1 = (unsigned int)f2bf(cv[2]) | ((unsigned int)f2bf(cv[3]) << 16);
      uint2 pk; pk.x = p0; pk.y = p1;
      *(uint2*)&c_out[((e0 + tr * 4 + r) * 128 + cg0) >> 1] = pk;
    }
  }
  __syncthreads();
  for (int i = tid; i < 512; i += 256) {
    int row = i >> 3, h = i & 7;
    float s = scoreAcc[row][h];
    s = fminf(fmaxf(s, -5.f), 5.f);
    float es = expf(s);
    escore[(e0 + row) * 8 + h] = es;
    atomicAdd(&den[ei[e0 + row] * 8 + h], es);
  }
}

// ---------------- edge kernel B: t = c@w2.T + b2 + conn, BN-c stats ----------------
__global__ __launch_bounds__(256) void k_edgeB(
    const unsigned int* __restrict__ c_bf, const float* __restrict__ conn,
    const float* __restrict__ w2, const float* __restrict__ b2,
    float* __restrict__ t_out, float* __restrict__ bnc_sums) {
  __shared__ float aS[64][132];
  __shared__ float wT[128][64];
  __shared__ float csum[128], csq[128];
  const int tid = threadIdx.x;
  const int e0 = blockIdx.x * 64;
  for (int i = tid; i < 2048; i += 256) {
    int row = i >> 5, q = i & 31;
    uint2 v = *(const uint2*)&c_bf[(e0 + row) * 64 + q * 2];
    aS[row][q * 4 + 0] = bfl(v.x);
    aS[row][q * 4 + 1] = bfh(v.x);
    aS[row][q * 4 + 2] = bfl(v.y);
    aS[row][q * 4 + 3] = bfh(v.y);
  }
  if (tid < 128) { csum[tid] = 0.f; csq[tid] = 0.f; }
  const int tr = tid >> 4, tc = tid & 15;
  __syncthreads();
#pragma unroll 1
  for (int j = 0; j < 2; ++j) {
    stage_w128(w2, j * 64, 128, 0, wT, tid);
    __syncthreads();
    f4 acc[4] = {};
    mm64(aS, wT, tr, tc, acc);
    const int cg0 = j * 64 + tc * 4;
    f4 bias = *(const f4*)&b2[cg0];
    f4 cs = {}, cq = {};
#pragma unroll
    for (int r = 0; r < 4; ++r) {
      f4 cn = *(const f4*)&conn[(e0 + tr * 4 + r) * 128 + cg0];
      f4 t = acc[r] + bias + cn;
      *(f4*)&t_out[(e0 + tr * 4 + r) * 128 + cg0] = t;
      cs += t;
      cq += t * t;
    }
#pragma unroll
    for (int c = 0; c < 4; ++c) {
      atomicAdd(&csum[cg0 + c], cs[c]);
      atomicAdd(&csq[cg0 + c], cq[c]);
    }
    __syncthreads();
  }
  if (tid < 128) {
    atomicAdd(&bnc_sums[tid], csum[tid]);
    atomicAdd(&bnc_sums[128 + tid], csq[tid]);
  }
}

// ---------------- CSR build ----------------
__global__ void k_deg(const int* __restrict__ ei, int* __restrict__ deg) {
  int e = blockIdx.x * 256 + threadIdx.x;
  if (e < N_EDGES) atomicAdd(&deg[ei[e]], 1);
}

__global__ __launch_bounds__(1024) void k_scan(const int* __restrict__ deg,
                                               int* __restrict__ rowptr,
                                               int* __restrict__ cursor) {
  __shared__ int ls[1024];
  const int t = threadIdx.x;
  const int base = t * 10;
  int s = 0;
#pragma unroll
  for (int i = 0; i < 10; ++i) {
    int idx = base + i;
    s += (idx < N_NODES) ? deg[idx] : 0;
  }
  ls[t] = s;
  __syncthreads();
  for (int off = 1; off < 1024; off <<= 1) {
    int v = (t >= off) ? ls[t - off] : 0;
    __syncthreads();
    ls[t] += v;
    __syncthreads();
  }
  int run = ls[t] - s;  // exclusive prefix
#pragma unroll
  for (int i = 0; i < 10; ++i) {
    int idx = base + i;
    if (idx < N_NODES) {
      rowptr[idx] = run;
      cursor[idx] = run;
      run += deg[idx];
    }
  }
  if (t == 1023) rowptr[N_NODES] = ls[1023];
}

__global__ void k_scatter(const int* __restrict__ ei, int* __restrict__ cursor,
                          int* __restrict__ elist) {
  int e = blockIdx.x * 256 + threadIdx.x;
  if (e < N_EDGES) {
    int pos = atomicAdd(&cursor[ei[e]], 1);
    elist[pos] = e;
  }
}

// ---------------- BN helpers ----------------
__global__ void k_bnfin(const float* __restrict__ sums, const float* __restrict__ g,
                        const float* __restrict__ bta, float inv_n,
                        float* __restrict__ ss) {
  int c = threadIdx.x;  // 128
  float mu = sums[c] * inv_n;
  float var = sums[128 + c] * inv_n - mu * mu;
  float sc = g[c] / sqrtf(var + 1e-5f);
  ss[c] = sc;
  ss[128 + c] = bta[c] - mu * sc;
}

__global__ void k_bnapply(const float* __restrict__ in, const float* __restrict__ ss,
                          float* __restrict__ out, int n4, int relu) {
  int i = blockIdx.x * 256 + threadIdx.x;
  const int stride = gridDim.x * 256;
  for (; i < n4; i += stride) {
    int c = (i & 31) * 4;
    f4 v = *(const f4*)&in[i * 4];
    f4 sc = *(const f4*)&ss[c];
    f4 sh = *(const f4*)&ss[128 + c];
    v = v * sc + sh;
    if (relu) {
#pragma unroll
      for (int t = 0; t < 4; ++t) v[t] = fmaxf(v[t], 0.f);
    }
    *(f4*)&out[i * 4] = v;
  }
}

__global__ __launch_bounds__(256) void k_colstats(const float* __restrict__ src,
                                                  int nrows, float* __restrict__ out) {
  __shared__ float rs[128], rq[128];
  const int c = threadIdx.x & 127, rr = threadIdx.x >> 7;
  const int r0 = blockIdx.x * 256;
  float s = 0.f, q = 0.f;
  int rend = r0 + 256; if (rend > nrows) rend = nrows;
  for (int r = r0 + rr; r < rend; r += 2) {
    float v = src[r * 128 + c];
    s += v;
    q += v * v;
  }
  if (rr == 1) { rs[c] = s; rq[c] = q; }
  __syncthreads();
  if (rr == 0) {
    atomicAdd(&out[c], s + rs[c]);
    atomicAdd(&out[128 + c], q + rq[c]);
  }
}

// ---------------- aggregation (gather by dst), deg_coef, h_res ----------------
__global__ __launch_bounds__(256) void k_agg(
    const int* __restrict__ rowptr, const int* __restrict__ elist,
    const int* __restrict__ ei, const float* __restrict__ escore,
    const float* __restrict__ den, const float* __restrict__ c2,
    const float* __restrict__ qkv, const float* __restrict__ x,
    const float* __restrict__ sqrtdeg, const float* __restrict__ degc,
    float* __restrict__ hres) {
  const int lane = threadIdx.x & 63;
  const int n = blockIdx.x * 4 + (threadIdx.x >> 6);
  if (n >= N_NODES) return;
  const int st = rowptr[n], en = rowptr[n + 1];
  const int head = lane >> 3;  // (2*lane)/16
  const float invd = 1.f / (den[n * 8 + head] + 1e-16f);
  f2 acc = {};
  for (int idx = st; idx < en; ++idx) {
    const int e = elist[idx];
    const float al = escore[e * 8 + head] * invd;
    const int src = ei[N_EDGES + e];
    f2 cv = *(const f2*)&c2[e * 128 + lane * 2];
    f2 vv = *(const f2*)&qkv[src * 384 + 256 + lane * 2];
    acc += al * (cv + vv);
  }
  const float sd = sqrtdeg[n];
  const int c0 = lane * 2;
  f2 d0 = { degc[c0 * 2], degc[(c0 + 1) * 2] };
  f2 d1 = { degc[c0 * 2 + 1], degc[(c0 + 1) * 2 + 1] };
  f2 xr = *(const f2*)&x[n * 128 + c0];
  f2 hr = acc * (d0 + sd * d1) + xr;
  *(f2*)&hres[n * 128 + c0] = hr;
}

// ---------------- FFN ----------------
__global__ __launch_bounds__(256) void k_ffn1(const float* __restrict__ hres,
                                              const float* __restrict__ ss,
                                              const float* __restrict__ w,
                                              const float* __restrict__ b,
                                              float* __restrict__ mid) {
  __shared__ float aS[64][132];
  __shared__ float wT[128][64];
  const int tid = threadIdx.x;
  const int r0 = blockIdx.x * 64;
  for (int i = tid; i < 2048; i += 256) {
    int row = i >> 5, kq = i & 31;
    int gr = r0 + row; if (gr > N_NODES - 1) gr = N_NODES - 1;
    f4 v = *(const f4*)&hres[gr * 128 + kq * 4];
    f4 sc = *(const f4*)&ss[kq * 4];
    f4 sh = *(const f4*)&ss[128 + kq * 4];
    *(f4*)&aS[row][kq * 4] = v * sc + sh;
  }
  const int tr = tid >> 4, tc = tid & 15;
#pragma unroll 1
  for (int ch = 0; ch < 4; ++ch) {
    __syncthreads();
    stage_w128(w, ch * 64, 128, 0, wT, tid);
    __syncthreads();
    f4 acc[4] = {};
    mm64(aS, wT, tr, tc, acc);
    f4 bias = *(const f4*)&b[ch * 64 + tc * 4];
#pragma unroll
    for (int r = 0; r < 4; ++r) {
      int gr = r0 + tr * 4 + r;
      if (gr < N_NODES) {
        f4 o = acc[r] + bias;
#pragma unroll
        for (int t = 0; t < 4; ++t) o[t] = fmaxf(o[t], 0.f);
        *(f4*)&mid[gr * 256 + ch * 64 + tc * 4] = o;
      }
    }
  }
}

__global__ __launch_bounds__(256) void k_ffn2(const float* __restrict__ mid,
                                              const float* __restrict__ w,
                                              const float* __restrict__ b,
                                              const float* __restrict__ hres,
                                              float* __restrict__ y) {
  __shared__ float aS[32][260];
  __shared__ float wT[128][64];
  const int tid = threadIdx.x;
  const int r0 = blockIdx.x * 32;
  for (int i = tid; i < 2048; i += 256) {
    int row = i >> 6, kq = i & 63;
    int gr = r0 + row; if (gr > N_NODES - 1) gr = N_NODES - 1;
    *(f4*)&aS[row][kq * 4] = *(const f4*)&mid[gr * 256 + kq * 4];
  }
  const int tr = tid >> 4, tc = tid & 15;  // rows 2tr..+1, cols 4tc..+3
#pragma unroll 1
  for (int j = 0; j < 2; ++j) {
    f4 acc[2] = {};
#pragma unroll 1
    for (int kc = 0; kc < 2; ++kc) {
      __syncthreads();
      stage_w128(w, j * 64, 256, kc * 128, wT, tid);
      __syncthreads();
#pragma unroll 4
      for (int k = 0; k < 128; k += 4) {
        f4 a0 = *(const f4*)&aS[tr * 2 + 0][kc * 128 + k];
        f4 a1 = *(const f4*)&aS[tr * 2 + 1][kc * 128 + k];
#pragma unroll
        for (int kk = 0; kk < 4; ++kk) {
          f4 bv = *(const f4*)&wT[k + kk][tc * 4];
          acc[0] += a0[kk] * bv;
          acc[1] += a1[kk] * bv;
        }
      }
    }
    const int cg0 = j * 64 + tc * 4;
    f4 bias = *(const f4*)&b[cg0];
#pragma unroll
    for (int r = 0; r < 2; ++r) {
      int gr = r0 + tr * 2 + r;
      if (gr < N_NODES) {
        f4 hv = *(const f4*)&hres[gr * 128 + cg0];
        f4 o = acc[r] + bias + hv;
        *(f4*)&y[gr * 128 + cg0] = o;
      }
    }
  }
}

extern "C" void kernel_launch(void* const* d_in, const int* in_sizes, int n_in,
                              void* d_out, int out_size, void* d_ws, size_t ws_size,
                              hipStream_t stream) {
  const float* x      = (const float*)d_in[0];
  const float* conn   = (const float*)d_in[1];
  const int*   ei     = (const int*)d_in[2];
  const float* sqrtdg = (const float*)d_in[3];
  const float* qkv_w  = (const float*)d_in[4];
  const float* qkv_b  = (const float*)d_in[5];
  const float* w1     = (const float*)d_in[6];
  const float* b1     = (const float*)d_in[7];
  const float* wscore = (const float*)d_in[8];
  const float* w2     = (const float*)d_in[9];
  const float* b2     = (const float*)d_in[10];
  const float* bncg   = (const float*)d_in[11];
  const float* bncb   = (const float*)d_in[12];
  const float* degc   = (const float*)d_in[13];
  const float* f1w    = (const float*)d_in[14];
  const float* f1b    = (const float*)d_in[15];
  const float* f2w    = (const float*)d_in[16];
  const float* f2b    = (const float*)d_in[17];
  const float* bn1g   = (const float*)d_in[18];
  const float* bn1b   = (const float*)d_in[19];
  const float* bn2g   = (const float*)d_in[20];
  const float* bn2b   = (const float*)d_in[21];

  float* ws  = (float*)d_ws;
  int*   wsi = (int*)d_ws;
  float* outF = (float*)d_out;
  float* t_c2 = outF + N_NODES * 128;  // c2 region of output doubles as t scratch

  (void)hipMemsetAsync(d_ws, 0, (size_t)ZERO_WORDS * 4, stream);

  k_qkv<<<dim3(157), dim3(256), 0, stream>>>(x, qkv_w, qkv_b, ws + OFF_QKV);
  k_deg<<<dim3(625), dim3(256), 0, stream>>>(ei, wsi + OFF_DEG);
  k_edgeA<<<dim3(2500), dim3(256), 0, stream>>>(conn, ei, ws + OFF_QKV, w1, b1, wscore,
                                                (unsigned int*)(wsi + OFF_CBF),
                                                ws + OFF_ESC, ws + OFF_DEN);
  k_edgeB<<<dim3(2500), dim3(256), 0, stream>>>((const unsigned int*)(wsi + OFF_CBF),
                                                conn, w2, b2, t_c2, ws + OFF_SUMS);
  k_scan<<<dim3(1), dim3(1024), 0, stream>>>(wsi + OFF_DEG, wsi + OFF_ROWPTR,
                                             wsi + OFF_CURSOR);
  k_scatter<<<dim3(625), dim3(256), 0, stream>>>(ei, wsi + OFF_CURSOR, wsi + OFF_ELIST);
  k_bnfin<<<dim3(1), dim3(128), 0, stream>>>(ws + OFF_SUMS, bncg, bncb,
                                             1.f / N_EDGES, ws + OFF_SS);
  k_bnapply<<<dim3(2048), dim3(256), 0, stream>>>(t_c2, ws + OFF_SS, t_c2,
                                                  N_EDGES * 128 / 4, 1);
  k_agg<<<dim3(2500), dim3(256), 0, stream>>>(wsi + OFF_ROWPTR, wsi + OFF_ELIST, ei,
                                              ws + OFF_ESC, ws + OFF_DEN, t_c2,
                                              ws + OFF_QKV, x, sqrtdg, degc,
                                              ws + OFF_HRES);
  k_colstats<<<dim3(40), dim3(256), 0, stream>>>(ws + OFF_HRES, N_NODES,
                                                 ws + OFF_SUMS + 256);
  k_bnfin<<<dim3(1), dim3(128), 0, stream>>>(ws + OFF_SUMS + 256, bn1g, bn1b,
                                             1.f / N_NODES, ws + OFF_SS + 256);
  k_ffn1<<<dim3(157), dim3(256), 0, stream>>>(ws + OFF_HRES, ws + OFF_SS + 256,
                                              f1w, f1b, ws + OFF_MID);
  k_ffn2<<<dim3(313), dim3(256), 0, stream>>>(ws + OFF_MID, f2w, f2b, ws + OFF_HRES,
                                              ws + OFF_Y);
  k_colstats<<<dim3(40), dim3(256), 0, stream>>>(ws + OFF_Y, N_NODES,
                                                 ws + OFF_SUMS + 512);
  k_bnfin<<<dim3(1), dim3(128), 0, stream>>>(ws + OFF_SUMS + 512, bn2g, bn2b,
                                             1.f / N_NODES, ws + OFF_SS + 512);
  k_bnapply<<<dim3(1250), dim3(256), 0, stream>>>(ws + OFF_Y, ws + OFF_SS + 512,
                                                  outF, N_NODES * 128 / 4, 0);
}

// Round 2
// 598.280 us; speedup vs baseline: 1.2938x; 1.2938x over previous
//
#include <hip/hip_runtime.h>
#include <math.h>

typedef float f4 __attribute__((ext_vector_type(4)));
typedef float f2 __attribute__((ext_vector_type(2)));
typedef short bf16x8 __attribute__((ext_vector_type(8)));
typedef float f32x4v __attribute__((ext_vector_type(4)));
typedef unsigned short u16x4 __attribute__((ext_vector_type(4)));

#define N_NODES 10000
#define N_EDGES 160000

// ---- workspace layout (units: 4-byte words) ----
#define OFF_DEN     0          // 80000 floats (N*8) softmax denominators   [zeroed]
#define OFF_SUMS    80000      // 768: bnc s/sq | bn1 s/sq | bn2 s/sq       [zeroed]
#define OFF_DEG     80768      // 10000 int degrees                         [zeroed]
#define ZERO_WORDS  90768
#define OFF_ROWPTR  90768      // 10001 int
#define OFF_CURSOR  100772     // 10000 int
#define OFF_ELIST   110772     // 160000 int
#define OFF_SS      270772     // 768: bnc scale/shift | bn1 | bn2
#define OFF_QKV     271544     // 3,840,000 f32 (N x 384)
#define OFF_ESC     4111544    // 1,280,000 f32 (E x 8) exp(score)
#define OFF_HRES    5391544    // 1,280,000 f32 (N x 128)
#define OFF_Y       6671544    // 1,280,000 f32 (N x 128) pre-BN2
#define OFF_MID     7951544    // 2,560,000 f32 (N x 256) ffn mid
#define OFF_WBF     10511544   // bf16 weights: w1bf 16384 words, w2bf 8192 words

__device__ __forceinline__ unsigned short f2bf(float f) {
  unsigned int u = __float_as_uint(f);
  u = (u + 0x7fffu + ((u >> 16) & 1u)) >> 16;
  return (unsigned short)u;
}
__device__ __forceinline__ float bf2f(unsigned short p) {
  return __uint_as_float(((unsigned int)p) << 16);
}

// ---------------- weight fp32 -> bf16 prep ----------------
__global__ void k_cvt(const float* __restrict__ w1, const float* __restrict__ w2,
                      unsigned short* __restrict__ w1bf,
                      unsigned short* __restrict__ w2bf) {
  int i = blockIdx.x * 256 + threadIdx.x;
  if (i < 32768) w1bf[i] = f2bf(w1[i]);
  if (i < 16384) w2bf[i] = f2bf(w2[i]);
}

// ---------------- fused edge kernel (MFMA) ----------------
// Per 64-edge block:
//   GEMM1: Eh = conn@w1.T (64x256, bf16 MFMA, 4 waves x 32-col strips)
//   epi1 : c = relu(sign*sqrt((Q[dst]+K[src])*Ew)+Eb); per-head score shfl-reduce;
//          c -> swizzled LDS bf16
//   GEMM2: t = c@w2.T + b2 + conn (64x128, each wave 16 rows)
//   epi2 : t -> global, BN-c stats block-reduce; scores -> exp -> escore/den
__global__ __launch_bounds__(256, 3) void k_edge(
    const float* __restrict__ conn, const int* __restrict__ ei,
    const float* __restrict__ qkv, const unsigned short* __restrict__ w1bf,
    const unsigned short* __restrict__ w2bf, const float* __restrict__ b1,
    const float* __restrict__ b2, const float* __restrict__ wsc_g,
    float* __restrict__ t_out, float* __restrict__ escore,
    float* __restrict__ den, float* __restrict__ bnc_sums) {
  __shared__ unsigned short connBF[8192];  // 64x128 bf16, XOR-swizzled
  __shared__ unsigned short qkBF[8192];    // 64x128 bf16, XOR-swizzled
  __shared__ unsigned short cBF[8192];     // 64x128 bf16, XOR-swizzled
  __shared__ float scoreAcc[64][8];
  __shared__ float wscS[128];
  __shared__ float csum[128], csq[128];
  const int tid = threadIdx.x;
  const int e0 = blockIdx.x * 64;

  if (tid < 128) { wscS[tid] = wsc_g[tid]; csum[tid] = 0.f; }
  else { csq[tid - 128] = 0.f; }

  // stage conn -> bf16 swizzled ; qk = Q[dst]+K[src] -> bf16 swizzled
#pragma unroll
  for (int it = 0; it < 8; ++it) {
    int i = tid + it * 256;
    int row = i >> 5, kq = i & 31;
    int wb = ((row * 256 + kq * 8) ^ ((row & 7) << 4)) >> 1;  // ushort index
    f4 cv = *(const f4*)&conn[(e0 + row) * 128 + kq * 4];
    u16x4 cp = { f2bf(cv[0]), f2bf(cv[1]), f2bf(cv[2]), f2bf(cv[3]) };
    *(u16x4*)&connBF[wb] = cp;
    int dst = ei[e0 + row], src = ei[N_EDGES + e0 + row];
    f4 qv = *(const f4*)&qkv[dst * 384 + kq * 4];
    f4 kv = *(const f4*)&qkv[src * 384 + 128 + kq * 4];
    f4 s = qv + kv;
    u16x4 sp = { f2bf(s[0]), f2bf(s[1]), f2bf(s[2]), f2bf(s[3]) };
    *(u16x4*)&qkBF[wb] = sp;
  }
  __syncthreads();

  const int w = tid >> 6;
  const int lq = (tid >> 4) & 3;  // lane quarter
  const int lr = tid & 15;        // lane residue

  // ---- GEMM1: wave w computes Ew cols [w*32, w*32+32) and Eb same strip ----
  f32x4v accW[2][4] = {};
  f32x4v accB[2][4] = {};
#pragma unroll
  for (int ks = 0; ks < 4; ++ks) {
    bf16x8 a[4];
#pragma unroll
    for (int rf = 0; rf < 4; ++rf) {
      int row = rf * 16 + lr;
      int off = ((row * 256 + ks * 64 + lq * 16) ^ ((row & 7) << 4)) >> 1;
      a[rf] = *(const bf16x8*)&connBF[off];
    }
#pragma unroll
    for (int cf = 0; cf < 2; ++cf) {
      int colW = w * 32 + cf * 16 + lr;  // output col (== w1 row)
      bf16x8 bW = *(const bf16x8*)&w1bf[colW * 128 + ks * 32 + lq * 8];
      bf16x8 bB = *(const bf16x8*)&w1bf[(128 + colW) * 128 + ks * 32 + lq * 8];
#pragma unroll
      for (int rf = 0; rf < 4; ++rf) {
        accW[cf][rf] =
            __builtin_amdgcn_mfma_f32_16x16x32_bf16(a[rf], bW, accW[cf][rf], 0, 0, 0);
        accB[cf][rf] =
            __builtin_amdgcn_mfma_f32_16x16x32_bf16(a[rf], bB, accB[cf][rf], 0, 0, 0);
      }
    }
  }
  // ---- epilogue 1: c, score, c->LDS ----
#pragma unroll
  for (int cf = 0; cf < 2; ++cf) {
    const int head = w * 2 + cf;
    const int col = w * 32 + cf * 16 + lr;
    const float wv = wscS[lr * 8 + head];  // wscore[dl=lr][head]
    const float bw = b1[col];
    const float bb = b1[128 + col];
#pragma unroll
    for (int rf = 0; rf < 4; ++rf) {
#pragma unroll
      for (int r = 0; r < 4; ++r) {
        int row = rf * 16 + lq * 4 + r;
        int qoff = ((row * 256 + col * 2) ^ ((row & 7) << 4)) >> 1;
        float qk = bf2f(qkBF[qoff]);
        float ew = accW[cf][rf][r] + bw;
        float eb = accB[cf][rf][r] + bb;
        float z = qk * ew;
        float cval = fmaxf(copysignf(sqrtf(fabsf(z)), z) + eb, 0.f);
        float sp = cval * wv;
        sp += __shfl_xor(sp, 1);
        sp += __shfl_xor(sp, 2);
        sp += __shfl_xor(sp, 4);
        sp += __shfl_xor(sp, 8);
        if (lr == 0) scoreAcc[row][head] = sp;
        cBF[qoff] = f2bf(cval);
      }
    }
  }
  __syncthreads();

  // ---- GEMM2: wave w owns rows [w*16, w*16+16), all 128 cols ----
  f32x4v acc2[8] = {};
#pragma unroll
  for (int ks = 0; ks < 4; ++ks) {
    int row = w * 16 + lr;
    int off = ((row * 256 + ks * 64 + lq * 16) ^ ((row & 7) << 4)) >> 1;
    bf16x8 a = *(const bf16x8*)&cBF[off];
#pragma unroll
    for (int cf = 0; cf < 8; ++cf) {
      bf16x8 b = *(const bf16x8*)&w2bf[(cf * 16 + lr) * 128 + ks * 32 + lq * 8];
      acc2[cf] = __builtin_amdgcn_mfma_f32_16x16x32_bf16(a, b, acc2[cf], 0, 0, 0);
    }
  }
  // ---- epilogue 2: t = acc + b2 + conn, stats ----
#pragma unroll
  for (int cf = 0; cf < 8; ++cf) {
    const int col = cf * 16 + lr;
    const float bias = b2[col];
    float sp = 0.f, qp = 0.f;
#pragma unroll
    for (int r = 0; r < 4; ++r) {
      int row = w * 16 + lq * 4 + r;
      float cn = conn[(e0 + row) * 128 + col];
      float t = acc2[cf][r] + bias + cn;
      t_out[(e0 + row) * 128 + col] = t;
      sp += t;
      qp += t * t;
    }
    sp += __shfl_xor(sp, 16);
    sp += __shfl_xor(sp, 32);
    qp += __shfl_xor(qp, 16);
    qp += __shfl_xor(qp, 32);
    if (lq == 0) {
      atomicAdd(&csum[col], sp);
      atomicAdd(&csq[col], qp);
    }
  }
  __syncthreads();

  if (tid < 128) {
    atomicAdd(&bnc_sums[tid], csum[tid]);
    atomicAdd(&bnc_sums[128 + tid], csq[tid]);
  }
  for (int i = tid; i < 512; i += 256) {
    int row = i >> 3, h = i & 7;
    float s = fminf(fmaxf(scoreAcc[row][h], -5.f), 5.f);
    float es = expf(s);
    escore[(e0 + row) * 8 + h] = es;
    atomicAdd(&den[ei[e0 + row] * 8 + h], es);
  }
}

// B-chunk stage: w row-major [rows][rowstride], stage 64 rows transposed to wT[128][64]
__device__ __forceinline__ void stage_w128(const float* __restrict__ w, int rowbase,
                                           int rowstride, int koff,
                                           float (*wT)[64], int tid) {
  for (int i = tid; i < 2048; i += 256) {
    int col = i & 63, k4 = i >> 6;
    f4 v = *(const f4*)&w[(rowbase + col) * rowstride + koff + k4 * 4];
    wT[k4 * 4 + 0][col] = v[0];
    wT[k4 * 4 + 1][col] = v[1];
    wT[k4 * 4 + 2][col] = v[2];
    wT[k4 * 4 + 3][col] = v[3];
  }
}

__device__ __forceinline__ void mm64(const float (*aS)[132], const float (*wT)[64],
                                     int tr, int tc, f4 acc[4]) {
#pragma unroll 4
  for (int k = 0; k < 128; k += 4) {
    f4 a0 = *(const f4*)&aS[tr * 4 + 0][k];
    f4 a1 = *(const f4*)&aS[tr * 4 + 1][k];
    f4 a2 = *(const f4*)&aS[tr * 4 + 2][k];
    f4 a3 = *(const f4*)&aS[tr * 4 + 3][k];
#pragma unroll
    for (int kk = 0; kk < 4; ++kk) {
      f4 b = *(const f4*)&wT[k + kk][tc * 4];
      acc[0] += a0[kk] * b;
      acc[1] += a1[kk] * b;
      acc[2] += a2[kk] * b;
      acc[3] += a3[kk] * b;
    }
  }
}

// ---------------- qkv = x @ qkv_w.T + qkv_b ----------------
__global__ __launch_bounds__(256) void k_qkv(const float* __restrict__ x,
                                             const float* __restrict__ w,
                                             const float* __restrict__ b,
                                             float* __restrict__ out) {
  __shared__ float aS[64][132];
  __shared__ float wT[128][64];
  const int tid = threadIdx.x;
  const int r0 = blockIdx.x * 64;
  for (int i = tid; i < 2048; i += 256) {
    int row = i >> 5, kq = i & 31;
    int gr = r0 + row; if (gr > N_NODES - 1) gr = N_NODES - 1;
    *(f4*)&aS[row][kq * 4] = *(const f4*)&x[gr * 128 + kq * 4];
  }
  const int tr = tid >> 4, tc = tid & 15;
#pragma unroll 1
  for (int ch = 0; ch < 6; ++ch) {
    __syncthreads();
    stage_w128(w, ch * 64, 128, 0, wT, tid);
    __syncthreads();
    f4 acc[4] = {};
    mm64(aS, wT, tr, tc, acc);
    f4 bias = *(const f4*)&b[ch * 64 + tc * 4];
#pragma unroll
    for (int r = 0; r < 4; ++r) {
      int gr = r0 + tr * 4 + r;
      if (gr < N_NODES) {
        f4 o = acc[r] + bias;
        *(f4*)&out[gr * 384 + ch * 64 + tc * 4] = o;
      }
    }
  }
}

// ---------------- CSR build ----------------
__global__ void k_deg(const int* __restrict__ ei, int* __restrict__ deg) {
  int e = blockIdx.x * 256 + threadIdx.x;
  if (e < N_EDGES) atomicAdd(&deg[ei[e]], 1);
}

__global__ __launch_bounds__(1024) void k_scan(const int* __restrict__ deg,
                                               int* __restrict__ rowptr,
                                               int* __restrict__ cursor) {
  __shared__ int ls[1024];
  const int t = threadIdx.x;
  const int base = t * 10;
  int s = 0;
#pragma unroll
  for (int i = 0; i < 10; ++i) {
    int idx = base + i;
    s += (idx < N_NODES) ? deg[idx] : 0;
  }
  ls[t] = s;
  __syncthreads();
  for (int off = 1; off < 1024; off <<= 1) {
    int v = (t >= off) ? ls[t - off] : 0;
    __syncthreads();
    ls[t] += v;
    __syncthreads();
  }
  int run = ls[t] - s;
#pragma unroll
  for (int i = 0; i < 10; ++i) {
    int idx = base + i;
    if (idx < N_NODES) {
      rowptr[idx] = run;
      cursor[idx] = run;
      run += deg[idx];
    }
  }
  if (t == 1023) rowptr[N_NODES] = ls[1023];
}

__global__ void k_scatter(const int* __restrict__ ei, int* __restrict__ cursor,
                          int* __restrict__ elist) {
  int e = blockIdx.x * 256 + threadIdx.x;
  if (e < N_EDGES) {
    int pos = atomicAdd(&cursor[ei[e]], 1);
    elist[pos] = e;
  }
}

// ---------------- BN helpers ----------------
__global__ void k_bnfin(const float* __restrict__ sums, const float* __restrict__ g,
                        const float* __restrict__ bta, float inv_n,
                        float* __restrict__ ss) {
  int c = threadIdx.x;  // 128
  float mu = sums[c] * inv_n;
  float var = sums[128 + c] * inv_n - mu * mu;
  float sc = g[c] / sqrtf(var + 1e-5f);
  ss[c] = sc;
  ss[128 + c] = bta[c] - mu * sc;
}

__global__ void k_bnapply(const float* __restrict__ in, const float* __restrict__ ss,
                          float* __restrict__ out, int n4, int relu) {
  int i = blockIdx.x * 256 + threadIdx.x;
  const int stride = gridDim.x * 256;
  for (; i < n4; i += stride) {
    int c = (i & 31) * 4;
    f4 v = *(const f4*)&in[i * 4];
    f4 sc = *(const f4*)&ss[c];
    f4 sh = *(const f4*)&ss[128 + c];
    v = v * sc + sh;
    if (relu) {
#pragma unroll
      for (int t = 0; t < 4; ++t) v[t] = fmaxf(v[t], 0.f);
    }
    *(f4*)&out[i * 4] = v;
  }
}

__global__ __launch_bounds__(256) void k_colstats(const float* __restrict__ src,
                                                  int nrows, float* __restrict__ out) {
  __shared__ float rs[128], rq[128];
  const int c = threadIdx.x & 127, rr = threadIdx.x >> 7;
  const int r0 = blockIdx.x * 256;
  float s = 0.f, q = 0.f;
  int rend = r0 + 256; if (rend > nrows) rend = nrows;
  for (int r = r0 + rr; r < rend; r += 2) {
    float v = src[r * 128 + c];
    s += v;
    q += v * v;
  }
  if (rr == 1) { rs[c] = s; rq[c] = q; }
  __syncthreads();
  if (rr == 0) {
    atomicAdd(&out[c], s + rs[c]);
    atomicAdd(&out[128 + c], q + rq[c]);
  }
}

// ---------------- aggregation ----------------
__global__ __launch_bounds__(256) void k_agg(
    const int* __restrict__ rowptr, const int* __restrict__ elist,
    const int* __restrict__ ei, const float* __restrict__ escore,
    const float* __restrict__ den, const float* __restrict__ c2,
    const float* __restrict__ qkv, const float* __restrict__ x,
    const float* __restrict__ sqrtdeg, const float* __restrict__ degc,
    float* __restrict__ hres) {
  const int lane = threadIdx.x & 63;
  const int n = blockIdx.x * 4 + (threadIdx.x >> 6);
  if (n >= N_NODES) return;
  const int st = rowptr[n], en = rowptr[n + 1];
  const int head = lane >> 3;
  const float invd = 1.f / (den[n * 8 + head] + 1e-16f);
  f2 acc = {};
  for (int idx = st; idx < en; ++idx) {
    const int e = elist[idx];
    const float al = escore[e * 8 + head] * invd;
    const int src = ei[N_EDGES + e];
    f2 cv = *(const f2*)&c2[e * 128 + lane * 2];
    f2 vv = *(const f2*)&qkv[src * 384 + 256 + lane * 2];
    acc += al * (cv + vv);
  }
  const float sd = sqrtdeg[n];
  const int c0 = lane * 2;
  f2 d0 = { degc[c0 * 2], degc[(c0 + 1) * 2] };
  f2 d1 = { degc[c0 * 2 + 1], degc[(c0 + 1) * 2 + 1] };
  f2 xr = *(const f2*)&x[n * 128 + c0];
  f2 hr = acc * (d0 + sd * d1) + xr;
  *(f2*)&hres[n * 128 + c0] = hr;
}

// ---------------- FFN ----------------
__global__ __launch_bounds__(256) void k_ffn1(const float* __restrict__ hres,
                                              const float* __restrict__ ss,
                                              const float* __restrict__ w,
                                              const float* __restrict__ b,
                                              float* __restrict__ mid) {
  __shared__ float aS[64][132];
  __shared__ float wT[128][64];
  const int tid = threadIdx.x;
  const int r0 = blockIdx.x * 64;
  for (int i = tid; i < 2048; i += 256) {
    int row = i >> 5, kq = i & 31;
    int gr = r0 + row; if (gr > N_NODES - 1) gr = N_NODES - 1;
    f4 v = *(const f4*)&hres[gr * 128 + kq * 4];
    f4 sc = *(const f4*)&ss[kq * 4];
    f4 sh = *(const f4*)&ss[128 + kq * 4];
    *(f4*)&aS[row][kq * 4] = v * sc + sh;
  }
  const int tr = tid >> 4, tc = tid & 15;
#pragma unroll 1
  for (int ch = 0; ch < 4; ++ch) {
    __syncthreads();
    stage_w128(w, ch * 64, 128, 0, wT, tid);
    __syncthreads();
    f4 acc[4] = {};
    mm64(aS, wT, tr, tc, acc);
    f4 bias = *(const f4*)&b[ch * 64 + tc * 4];
#pragma unroll
    for (int r = 0; r < 4; ++r) {
      int gr = r0 + tr * 4 + r;
      if (gr < N_NODES) {
        f4 o = acc[r] + bias;
#pragma unroll
        for (int t = 0; t < 4; ++t) o[t] = fmaxf(o[t], 0.f);
        *(f4*)&mid[gr * 256 + ch * 64 + tc * 4] = o;
      }
    }
  }
}

__global__ __launch_bounds__(256) void k_ffn2(const float* __restrict__ mid,
                                              const float* __restrict__ w,
                                              const float* __restrict__ b,
                                              const float* __restrict__ hres,
                                              float* __restrict__ y) {
  __shared__ float aS[32][260];
  __shared__ float wT[128][64];
  const int tid = threadIdx.x;
  const int r0 = blockIdx.x * 32;
  for (int i = tid; i < 2048; i += 256) {
    int row = i >> 6, kq = i & 63;
    int gr = r0 + row; if (gr > N_NODES - 1) gr = N_NODES - 1;
    *(f4*)&aS[row][kq * 4] = *(const f4*)&mid[gr * 256 + kq * 4];
  }
  const int tr = tid >> 4, tc = tid & 15;
#pragma unroll 1
  for (int j = 0; j < 2; ++j) {
    f4 acc[2] = {};
#pragma unroll 1
    for (int kc = 0; kc < 2; ++kc) {
      __syncthreads();
      stage_w128(w, j * 64, 256, kc * 128, wT, tid);
      __syncthreads();
#pragma unroll 4
      for (int k = 0; k < 128; k += 4) {
        f4 a0 = *(const f4*)&aS[tr * 2 + 0][kc * 128 + k];
        f4 a1 = *(const f4*)&aS[tr * 2 + 1][kc * 128 + k];
#pragma unroll
        for (int kk = 0; kk < 4; ++kk) {
          f4 bv = *(const f4*)&wT[k + kk][tc * 4];
          acc[0] += a0[kk] * bv;
          acc[1] += a1[kk] * bv;
        }
      }
    }
    const int cg0 = j * 64 + tc * 4;
    f4 bias = *(const f4*)&b[cg0];
#pragma unroll
    for (int r = 0; r < 2; ++r) {
      int gr = r0 + tr * 2 + r;
      if (gr < N_NODES) {
        f4 hv = *(const f4*)&hres[gr * 128 + cg0];
        f4 o = acc[r] + bias + hv;
        *(f4*)&y[gr * 128 + cg0] = o;
      }
    }
  }
}

extern "C" void kernel_launch(void* const* d_in, const int* in_sizes, int n_in,
                              void* d_out, int out_size, void* d_ws, size_t ws_size,
                              hipStream_t stream) {
  const float* x      = (const float*)d_in[0];
  const float* conn   = (const float*)d_in[1];
  const int*   ei     = (const int*)d_in[2];
  const float* sqrtdg = (const float*)d_in[3];
  const float* qkv_w  = (const float*)d_in[4];
  const float* qkv_b  = (const float*)d_in[5];
  const float* w1     = (const float*)d_in[6];
  const float* b1     = (const float*)d_in[7];
  const float* wscore = (const float*)d_in[8];
  const float* w2     = (const float*)d_in[9];
  const float* b2     = (const float*)d_in[10];
  const float* bncg   = (const float*)d_in[11];
  const float* bncb   = (const float*)d_in[12];
  const float* degc   = (const float*)d_in[13];
  const float* f1w    = (const float*)d_in[14];
  const float* f1b    = (const float*)d_in[15];
  const float* f2w    = (const float*)d_in[16];
  const float* f2b    = (const float*)d_in[17];
  const float* bn1g   = (const float*)d_in[18];
  const float* bn1b   = (const float*)d_in[19];
  const float* bn2g   = (const float*)d_in[20];
  const float* bn2b   = (const float*)d_in[21];

  float* ws  = (float*)d_ws;
  int*   wsi = (int*)d_ws;
  float* outF = (float*)d_out;
  float* t_c2 = outF + N_NODES * 128;  // c2 region of output doubles as t scratch
  unsigned short* w1bf = (unsigned short*)(wsi + OFF_WBF);
  unsigned short* w2bf = (unsigned short*)(wsi + OFF_WBF + 16384);

  (void)hipMemsetAsync(d_ws, 0, (size_t)ZERO_WORDS * 4, stream);

  k_cvt<<<dim3(128), dim3(256), 0, stream>>>(w1, w2, w1bf, w2bf);
  k_qkv<<<dim3(157), dim3(256), 0, stream>>>(x, qkv_w, qkv_b, ws + OFF_QKV);
  k_deg<<<dim3(625), dim3(256), 0, stream>>>(ei, wsi + OFF_DEG);
  k_edge<<<dim3(2500), dim3(256), 0, stream>>>(conn, ei, ws + OFF_QKV, w1bf, w2bf,
                                               b1, b2, wscore, t_c2,
                                               ws + OFF_ESC, ws + OFF_DEN,
                                               ws + OFF_SUMS);
  k_scan<<<dim3(1), dim3(1024), 0, stream>>>(wsi + OFF_DEG, wsi + OFF_ROWPTR,
                                             wsi + OFF_CURSOR);
  k_scatter<<<dim3(625), dim3(256), 0, stream>>>(ei, wsi + OFF_CURSOR, wsi + OFF_ELIST);
  k_bnfin<<<dim3(1), dim3(128), 0, stream>>>(ws + OFF_SUMS, bncg, bncb,
                                             1.f / N_EDGES, ws + OFF_SS);
  k_bnapply<<<dim3(2048), dim3(256), 0, stream>>>(t_c2, ws + OFF_SS, t_c2,
                                                  N_EDGES * 128 / 4, 1);
  k_agg<<<dim3(2500), dim3(256), 0, stream>>>(wsi + OFF_ROWPTR, wsi + OFF_ELIST, ei,
                                              ws + OFF_ESC, ws + OFF_DEN, t_c2,
                                              ws + OFF_QKV, x, sqrtdg, degc,
                                              ws + OFF_HRES);
  k_colstats<<<dim3(40), dim3(256), 0, stream>>>(ws + OFF_HRES, N_NODES,
                                                 ws + OFF_SUMS + 256);
  k_bnfin<<<dim3(1), dim3(128), 0, stream>>>(ws + OFF_SUMS + 256, bn1g, bn1b,
                                             1.f / N_NODES, ws + OFF_SS + 256);
  k_ffn1<<<dim3(157), dim3(256), 0, stream>>>(ws + OFF_HRES, ws + OFF_SS + 256,
                                              f1w, f1b, ws + OFF_MID);
  k_ffn2<<<dim3(313), dim3(256), 0, stream>>>(ws + OFF_MID, f2w, f2b, ws + OFF_HRES,
                                              ws + OFF_Y);
  k_colstats<<<dim3(40), dim3(256), 0, stream>>>(ws + OFF_Y, N_NODES,
                                                 ws + OFF_SUMS + 512);
  k_bnfin<<<dim3(1), dim3(128), 0, stream>>>(ws + OFF_SUMS + 512, bn2g, bn2b,
                                             1.f / N_NODES, ws + OFF_SS + 512);
  k_bnapply<<<dim3(1250), dim3(256), 0, stream>>>(ws + OFF_Y, ws + OFF_SS + 512,
                                                  outF, N_NODES * 128 / 4, 0);
}

// Round 3
// 566.294 us; speedup vs baseline: 1.3669x; 1.0565x over previous
//
#include <hip/hip_runtime.h>
#include <math.h>

typedef float f4 __attribute__((ext_vector_type(4)));
typedef float f2 __attribute__((ext_vector_type(2)));
typedef short bf16x8 __attribute__((ext_vector_type(8)));
typedef float f32x4v __attribute__((ext_vector_type(4)));
typedef unsigned short u16x4 __attribute__((ext_vector_type(4)));

#define N_NODES 10000
#define N_EDGES 160000

// ---- workspace layout (units: 4-byte words) ----
#define OFF_DEN     0          // 80000 floats (N*8) softmax denominators   [zeroed]
#define OFF_SUMS    80000      // 768: bnc s/sq | bn1 s/sq | bn2 s/sq       [zeroed]
#define OFF_DEG     80768      // 10000 int degrees                         [zeroed]
#define ZERO_WORDS  90768
#define OFF_ROWPTR  90768      // 10001 int
#define OFF_CURSOR  100772     // 10000 int
#define OFF_ELIST   110772     // 160000 int
#define OFF_SS      270772     // 768: bnc scale/shift | bn1 | bn2
#define OFF_QKV     271544     // 3,840,000 f32 (N x 384)
#define OFF_ESC     4111544    // 1,280,000 f32 (E x 8) exp(score)
#define OFF_HRES    5391544    // 1,280,000 f32 (N x 128)
#define OFF_Y       6671544    // 1,280,000 f32 (N x 128) pre-BN2
#define OFF_MID     7951544    // 2,560,000 f32 (N x 256) ffn mid
#define OFF_WBF     10511544   // bf16 weights: w1bf 16384 words, w2bf 8192 words

__device__ __forceinline__ unsigned short f2bf(float f) {
  unsigned int u = __float_as_uint(f);
  u = (u + 0x7fffu + ((u >> 16) & 1u)) >> 16;
  return (unsigned short)u;
}
__device__ __forceinline__ float bf2f(unsigned short p) {
  return __uint_as_float(((unsigned int)p) << 16);
}

// ---------------- weight fp32 -> bf16 prep ----------------
__global__ void k_cvt(const float* __restrict__ w1, const float* __restrict__ w2,
                      unsigned short* __restrict__ w1bf,
                      unsigned short* __restrict__ w2bf) {
  int i = blockIdx.x * 256 + threadIdx.x;
  if (i < 32768) w1bf[i] = f2bf(w1[i]);
  if (i < 16384) w2bf[i] = f2bf(w2[i]);
}

// ---------------- fused edge kernel (MFMA) ----------------
// Per 64-edge block:
//   GEMM1: Eh = conn@w1.T (64x256, bf16 MFMA, 4 waves x 32-col strips)
//   epi1 : c = relu(sign*sqrt((Q[dst]+K[src])*Ew)+Eb); per-head score shfl-reduce;
//          c overwrites qk in LDS (in-place -> saves 16KB LDS)
//   GEMM2: t = c@w2.T + b2 + conn(LDS) (64x128, each wave 16 rows)
//   epi2 : t -> global, BN-c stats block-reduce; scores -> exp -> escore/den
__global__ __launch_bounds__(256, 4) void k_edge(
    const float* __restrict__ conn, const int* __restrict__ ei,
    const float* __restrict__ qkv, const unsigned short* __restrict__ w1bf,
    const unsigned short* __restrict__ w2bf, const float* __restrict__ b1,
    const float* __restrict__ b2, const float* __restrict__ wsc_g,
    float* __restrict__ t_out, float* __restrict__ escore,
    float* __restrict__ den, float* __restrict__ bnc_sums) {
  __shared__ unsigned short connBF[8192];  // 64x128 bf16, XOR-swizzled
  __shared__ unsigned short qkcBF[8192];   // qk, overwritten by c in epi1
  __shared__ float scoreAcc[64][8];
  __shared__ float wscS[128];
  __shared__ float csum[128], csq[128];
  const int tid = threadIdx.x;
  const int e0 = blockIdx.x * 64;

  if (tid < 128) { wscS[tid] = wsc_g[tid]; csum[tid] = 0.f; }
  else { csq[tid - 128] = 0.f; }

  // stage conn -> bf16 swizzled ; qk = Q[dst]+K[src] -> bf16 swizzled
#pragma unroll
  for (int it = 0; it < 8; ++it) {
    int i = tid + it * 256;
    int row = i >> 5, kq = i & 31;
    int wb = ((row * 256 + kq * 8) ^ ((row & 7) << 4)) >> 1;  // ushort index
    f4 cv = *(const f4*)&conn[(e0 + row) * 128 + kq * 4];
    u16x4 cp = { f2bf(cv[0]), f2bf(cv[1]), f2bf(cv[2]), f2bf(cv[3]) };
    *(u16x4*)&connBF[wb] = cp;
    int dst = ei[e0 + row], src = ei[N_EDGES + e0 + row];
    f4 qv = *(const f4*)&qkv[dst * 384 + kq * 4];
    f4 kv = *(const f4*)&qkv[src * 384 + 128 + kq * 4];
    f4 s = qv + kv;
    u16x4 sp = { f2bf(s[0]), f2bf(s[1]), f2bf(s[2]), f2bf(s[3]) };
    *(u16x4*)&qkcBF[wb] = sp;
  }
  __syncthreads();

  const int w = tid >> 6;
  const int lq = (tid >> 4) & 3;  // lane quarter
  const int lr = tid & 15;        // lane residue

  // ---- GEMM1: wave w computes Ew cols [w*32, w*32+32) and Eb same strip ----
  f32x4v accW[2][4] = {};
  f32x4v accB[2][4] = {};
#pragma unroll
  for (int ks = 0; ks < 4; ++ks) {
    bf16x8 a[4];
#pragma unroll
    for (int rf = 0; rf < 4; ++rf) {
      int row = rf * 16 + lr;
      int off = ((row * 256 + ks * 64 + lq * 16) ^ ((row & 7) << 4)) >> 1;
      a[rf] = *(const bf16x8*)&connBF[off];
    }
#pragma unroll
    for (int cf = 0; cf < 2; ++cf) {
      int colW = w * 32 + cf * 16 + lr;  // output col (== w1 row)
      bf16x8 bW = *(const bf16x8*)&w1bf[colW * 128 + ks * 32 + lq * 8];
      bf16x8 bB = *(const bf16x8*)&w1bf[(128 + colW) * 128 + ks * 32 + lq * 8];
#pragma unroll
      for (int rf = 0; rf < 4; ++rf) {
        accW[cf][rf] =
            __builtin_amdgcn_mfma_f32_16x16x32_bf16(a[rf], bW, accW[cf][rf], 0, 0, 0);
        accB[cf][rf] =
            __builtin_amdgcn_mfma_f32_16x16x32_bf16(a[rf], bB, accB[cf][rf], 0, 0, 0);
      }
    }
  }
  // ---- epilogue 1: c = f(qk, Ew, Eb), score, c -> LDS (in place over qk) ----
#pragma unroll
  for (int cf = 0; cf < 2; ++cf) {
    const int head = w * 2 + cf;
    const int col = w * 32 + cf * 16 + lr;
    const float wv = wscS[lr * 8 + head];  // wscore[dl=lr][head]
    const float bw = b1[col];
    const float bb = b1[128 + col];
#pragma unroll
    for (int rf = 0; rf < 4; ++rf) {
#pragma unroll
      for (int r = 0; r < 4; ++r) {
        int row = rf * 16 + lq * 4 + r;
        int qoff = ((row * 256 + col * 2) ^ ((row & 7) << 4)) >> 1;
        float qk = bf2f(qkcBF[qoff]);
        float ew = accW[cf][rf][r] + bw;
        float eb = accB[cf][rf][r] + bb;
        float z = qk * ew;
        float cval = fmaxf(copysignf(sqrtf(fabsf(z)), z) + eb, 0.f);
        float sp = cval * wv;
        sp += __shfl_xor(sp, 1);
        sp += __shfl_xor(sp, 2);
        sp += __shfl_xor(sp, 4);
        sp += __shfl_xor(sp, 8);
        if (lr == 0) scoreAcc[row][head] = sp;
        qkcBF[qoff] = f2bf(cval);  // in-place: c overwrites qk
      }
    }
  }
  __syncthreads();

  // ---- GEMM2: wave w owns rows [w*16, w*16+16), all 128 cols ----
  f32x4v acc2[8] = {};
#pragma unroll
  for (int ks = 0; ks < 4; ++ks) {
    int row = w * 16 + lr;
    int off = ((row * 256 + ks * 64 + lq * 16) ^ ((row & 7) << 4)) >> 1;
    bf16x8 a = *(const bf16x8*)&qkcBF[off];
#pragma unroll
    for (int cf = 0; cf < 8; ++cf) {
      bf16x8 b = *(const bf16x8*)&w2bf[(cf * 16 + lr) * 128 + ks * 32 + lq * 8];
      acc2[cf] = __builtin_amdgcn_mfma_f32_16x16x32_bf16(a, b, acc2[cf], 0, 0, 0);
    }
  }
  // ---- epilogue 2: t = acc + b2 + conn(LDS), stats ----
#pragma unroll
  for (int cf = 0; cf < 8; ++cf) {
    const int col = cf * 16 + lr;
    const float bias = b2[col];
    float sp = 0.f, qp = 0.f;
#pragma unroll
    for (int r = 0; r < 4; ++r) {
      int row = w * 16 + lq * 4 + r;
      int coff = ((row * 256 + col * 2) ^ ((row & 7) << 4)) >> 1;
      float cn = bf2f(connBF[coff]);
      float t = acc2[cf][r] + bias + cn;
      t_out[(e0 + row) * 128 + col] = t;
      sp += t;
      qp += t * t;
    }
    sp += __shfl_xor(sp, 16);
    sp += __shfl_xor(sp, 32);
    qp += __shfl_xor(qp, 16);
    qp += __shfl_xor(qp, 32);
    if (lq == 0) {
      atomicAdd(&csum[col], sp);
      atomicAdd(&csq[col], qp);
    }
  }
  __syncthreads();

  if (tid < 128) {
    atomicAdd(&bnc_sums[tid], csum[tid]);
    atomicAdd(&bnc_sums[128 + tid], csq[tid]);
  }
  for (int i = tid; i < 512; i += 256) {
    int row = i >> 3, h = i & 7;
    float s = fminf(fmaxf(scoreAcc[row][h], -5.f), 5.f);
    float es = expf(s);
    escore[(e0 + row) * 8 + h] = es;
    atomicAdd(&den[ei[e0 + row] * 8 + h], es);
  }
}

// B-chunk stage: w row-major [rows][rowstride], stage 64 rows transposed to wT[128][64]
__device__ __forceinline__ void stage_w128(const float* __restrict__ w, int rowbase,
                                           int rowstride, int koff,
                                           float (*wT)[64], int tid) {
  for (int i = tid; i < 2048; i += 256) {
    int col = i & 63, k4 = i >> 6;
    f4 v = *(const f4*)&w[(rowbase + col) * rowstride + koff + k4 * 4];
    wT[k4 * 4 + 0][col] = v[0];
    wT[k4 * 4 + 1][col] = v[1];
    wT[k4 * 4 + 2][col] = v[2];
    wT[k4 * 4 + 3][col] = v[3];
  }
}

__device__ __forceinline__ void mm64(const float (*aS)[132], const float (*wT)[64],
                                     int tr, int tc, f4 acc[4]) {
#pragma unroll 4
  for (int k = 0; k < 128; k += 4) {
    f4 a0 = *(const f4*)&aS[tr * 4 + 0][k];
    f4 a1 = *(const f4*)&aS[tr * 4 + 1][k];
    f4 a2 = *(const f4*)&aS[tr * 4 + 2][k];
    f4 a3 = *(const f4*)&aS[tr * 4 + 3][k];
#pragma unroll
    for (int kk = 0; kk < 4; ++kk) {
      f4 b = *(const f4*)&wT[k + kk][tc * 4];
      acc[0] += a0[kk] * b;
      acc[1] += a1[kk] * b;
      acc[2] += a2[kk] * b;
      acc[3] += a3[kk] * b;
    }
  }
}

// ---------------- qkv = x @ qkv_w.T + qkv_b ----------------
__global__ __launch_bounds__(256) void k_qkv(const float* __restrict__ x,
                                             const float* __restrict__ w,
                                             const float* __restrict__ b,
                                             float* __restrict__ out) {
  __shared__ float aS[64][132];
  __shared__ float wT[128][64];
  const int tid = threadIdx.x;
  const int r0 = blockIdx.x * 64;
  for (int i = tid; i < 2048; i += 256) {
    int row = i >> 5, kq = i & 31;
    int gr = r0 + row; if (gr > N_NODES - 1) gr = N_NODES - 1;
    *(f4*)&aS[row][kq * 4] = *(const f4*)&x[gr * 128 + kq * 4];
  }
  const int tr = tid >> 4, tc = tid & 15;
#pragma unroll 1
  for (int ch = 0; ch < 6; ++ch) {
    __syncthreads();
    stage_w128(w, ch * 64, 128, 0, wT, tid);
    __syncthreads();
    f4 acc[4] = {};
    mm64(aS, wT, tr, tc, acc);
    f4 bias = *(const f4*)&b[ch * 64 + tc * 4];
#pragma unroll
    for (int r = 0; r < 4; ++r) {
      int gr = r0 + tr * 4 + r;
      if (gr < N_NODES) {
        f4 o = acc[r] + bias;
        *(f4*)&out[gr * 384 + ch * 64 + tc * 4] = o;
      }
    }
  }
}

// ---------------- CSR build ----------------
__global__ void k_deg(const int* __restrict__ ei, int* __restrict__ deg) {
  int e = blockIdx.x * 256 + threadIdx.x;
  if (e < N_EDGES) atomicAdd(&deg[ei[e]], 1);
}

__global__ __launch_bounds__(1024) void k_scan(const int* __restrict__ deg,
                                               int* __restrict__ rowptr,
                                               int* __restrict__ cursor) {
  __shared__ int ls[1024];
  const int t = threadIdx.x;
  const int base = t * 10;
  int s = 0;
#pragma unroll
  for (int i = 0; i < 10; ++i) {
    int idx = base + i;
    s += (idx < N_NODES) ? deg[idx] : 0;
  }
  ls[t] = s;
  __syncthreads();
  for (int off = 1; off < 1024; off <<= 1) {
    int v = (t >= off) ? ls[t - off] : 0;
    __syncthreads();
    ls[t] += v;
    __syncthreads();
  }
  int run = ls[t] - s;
#pragma unroll
  for (int i = 0; i < 10; ++i) {
    int idx = base + i;
    if (idx < N_NODES) {
      rowptr[idx] = run;
      cursor[idx] = run;
      run += deg[idx];
    }
  }
  if (t == 1023) rowptr[N_NODES] = ls[1023];
}

__global__ void k_scatter(const int* __restrict__ ei, int* __restrict__ cursor,
                          int* __restrict__ elist) {
  int e = blockIdx.x * 256 + threadIdx.x;
  if (e < N_EDGES) {
    int pos = atomicAdd(&cursor[ei[e]], 1);
    elist[pos] = e;
  }
}

// ---------------- BN helpers ----------------
__global__ void k_bnfin(const float* __restrict__ sums, const float* __restrict__ g,
                        const float* __restrict__ bta, float inv_n,
                        float* __restrict__ ss) {
  int c = threadIdx.x;  // 128
  float mu = sums[c] * inv_n;
  float var = sums[128 + c] * inv_n - mu * mu;
  float sc = g[c] / sqrtf(var + 1e-5f);
  ss[c] = sc;
  ss[128 + c] = bta[c] - mu * sc;
}

__global__ void k_bnapply(const float* __restrict__ in, const float* __restrict__ ss,
                          float* __restrict__ out, int n4, int relu) {
  int i = blockIdx.x * 256 + threadIdx.x;
  const int stride = gridDim.x * 256;
  for (; i < n4; i += stride) {
    int c = (i & 31) * 4;
    f4 v = *(const f4*)&in[i * 4];
    f4 sc = *(const f4*)&ss[c];
    f4 sh = *(const f4*)&ss[128 + c];
    v = v * sc + sh;
    if (relu) {
#pragma unroll
      for (int t = 0; t < 4; ++t) v[t] = fmaxf(v[t], 0.f);
    }
    *(f4*)&out[i * 4] = v;
  }
}

__global__ __launch_bounds__(256) void k_colstats(const float* __restrict__ src,
                                                  int nrows, float* __restrict__ out) {
  __shared__ float rs[128], rq[128];
  const int c = threadIdx.x & 127, rr = threadIdx.x >> 7;
  const int r0 = blockIdx.x * 256;
  float s = 0.f, q = 0.f;
  int rend = r0 + 256; if (rend > nrows) rend = nrows;
  for (int r = r0 + rr; r < rend; r += 2) {
    float v = src[r * 128 + c];
    s += v;
    q += v * v;
  }
  if (rr == 1) { rs[c] = s; rq[c] = q; }
  __syncthreads();
  if (rr == 0) {
    atomicAdd(&out[c], s + rs[c]);
    atomicAdd(&out[128 + c], q + rq[c]);
  }
}

// ---------------- aggregation: BN-c applied on the fly, c2 written in place ----
// 32 lanes per node (f4 cols), 8 nodes per block.
__global__ __launch_bounds__(256) void k_agg(
    const int* __restrict__ rowptr, const int* __restrict__ elist,
    const int* __restrict__ ei, const float* __restrict__ escore,
    const float* __restrict__ den, float* __restrict__ t_c2,
    const float* __restrict__ qkv, const float* __restrict__ x,
    const float* __restrict__ sqrtdeg, const float* __restrict__ degc,
    const float* __restrict__ ss, float* __restrict__ hres) {
  const int sl = threadIdx.x & 31;
  const int n = blockIdx.x * 8 + (threadIdx.x >> 5);
  if (n >= N_NODES) return;
  const int c0 = sl * 4;
  const int head = sl >> 2;
  const int st = rowptr[n], en = rowptr[n + 1];
  const float invd = 1.f / (den[n * 8 + head] + 1e-16f);
  const f4 sc = *(const f4*)&ss[c0];
  const f4 sh = *(const f4*)&ss[128 + c0];
  f4 acc = {};
  for (int idx = st; idx < en; ++idx) {
    const int e = elist[idx];
    const float al = escore[e * 8 + head] * invd;
    const int src = ei[N_EDGES + e];
    f4 tv = *(const f4*)&t_c2[e * 128 + c0];
    f4 vv = *(const f4*)&qkv[src * 384 + 256 + c0];
    f4 c2v = tv * sc + sh;
#pragma unroll
    for (int t = 0; t < 4; ++t) c2v[t] = fmaxf(c2v[t], 0.f);
    *(f4*)&t_c2[e * 128 + c0] = c2v;  // final c2 output (each edge visited once)
    acc += al * (c2v + vv);
  }
  const float sd = sqrtdeg[n];
  f4 d0 = { degc[c0 * 2], degc[c0 * 2 + 2], degc[c0 * 2 + 4], degc[c0 * 2 + 6] };
  f4 d1 = { degc[c0 * 2 + 1], degc[c0 * 2 + 3], degc[c0 * 2 + 5], degc[c0 * 2 + 7] };
  f4 xr = *(const f4*)&x[n * 128 + c0];
  f4 hr = acc * (d0 + sd * d1) + xr;
  *(f4*)&hres[n * 128 + c0] = hr;
}

// ---------------- FFN ----------------
__global__ __launch_bounds__(256) void k_ffn1(const float* __restrict__ hres,
                                              const float* __restrict__ ss,
                                              const float* __restrict__ w,
                                              const float* __restrict__ b,
                                              float* __restrict__ mid) {
  __shared__ float aS[64][132];
  __shared__ float wT[128][64];
  const int tid = threadIdx.x;
  const int r0 = blockIdx.x * 64;
  for (int i = tid; i < 2048; i += 256) {
    int row = i >> 5, kq = i & 31;
    int gr = r0 + row; if (gr > N_NODES - 1) gr = N_NODES - 1;
    f4 v = *(const f4*)&hres[gr * 128 + kq * 4];
    f4 sc = *(const f4*)&ss[kq * 4];
    f4 sh = *(const f4*)&ss[128 + kq * 4];
    *(f4*)&aS[row][kq * 4] = v * sc + sh;
  }
  const int tr = tid >> 4, tc = tid & 15;
#pragma unroll 1
  for (int ch = 0; ch < 4; ++ch) {
    __syncthreads();
    stage_w128(w, ch * 64, 128, 0, wT, tid);
    __syncthreads();
    f4 acc[4] = {};
    mm64(aS, wT, tr, tc, acc);
    f4 bias = *(const f4*)&b[ch * 64 + tc * 4];
#pragma unroll
    for (int r = 0; r < 4; ++r) {
      int gr = r0 + tr * 4 + r;
      if (gr < N_NODES) {
        f4 o = acc[r] + bias;
#pragma unroll
        for (int t = 0; t < 4; ++t) o[t] = fmaxf(o[t], 0.f);
        *(f4*)&mid[gr * 256 + ch * 64 + tc * 4] = o;
      }
    }
  }
}

__global__ __launch_bounds__(256) void k_ffn2(const float* __restrict__ mid,
                                              const float* __restrict__ w,
                                              const float* __restrict__ b,
                                              const float* __restrict__ hres,
                                              float* __restrict__ y) {
  __shared__ float aS[32][260];
  __shared__ float wT[128][64];
  const int tid = threadIdx.x;
  const int r0 = blockIdx.x * 32;
  for (int i = tid; i < 2048; i += 256) {
    int row = i >> 6, kq = i & 63;
    int gr = r0 + row; if (gr > N_NODES - 1) gr = N_NODES - 1;
    *(f4*)&aS[row][kq * 4] = *(const f4*)&mid[gr * 256 + kq * 4];
  }
  const int tr = tid >> 4, tc = tid & 15;
#pragma unroll 1
  for (int j = 0; j < 2; ++j) {
    f4 acc[2] = {};
#pragma unroll 1
    for (int kc = 0; kc < 2; ++kc) {
      __syncthreads();
      stage_w128(w, j * 64, 256, kc * 128, wT, tid);
      __syncthreads();
#pragma unroll 4
      for (int k = 0; k < 128; k += 4) {
        f4 a0 = *(const f4*)&aS[tr * 2 + 0][kc * 128 + k];
        f4 a1 = *(const f4*)&aS[tr * 2 + 1][kc * 128 + k];
#pragma unroll
        for (int kk = 0; kk < 4; ++kk) {
          f4 bv = *(const f4*)&wT[k + kk][tc * 4];
          acc[0] += a0[kk] * bv;
          acc[1] += a1[kk] * bv;
        }
      }
    }
    const int cg0 = j * 64 + tc * 4;
    f4 bias = *(const f4*)&b[cg0];
#pragma unroll
    for (int r = 0; r < 2; ++r) {
      int gr = r0 + tr * 2 + r;
      if (gr < N_NODES) {
        f4 hv = *(const f4*)&hres[gr * 128 + cg0];
        f4 o = acc[r] + bias + hv;
        *(f4*)&y[gr * 128 + cg0] = o;
      }
    }
  }
}

extern "C" void kernel_launch(void* const* d_in, const int* in_sizes, int n_in,
                              void* d_out, int out_size, void* d_ws, size_t ws_size,
                              hipStream_t stream) {
  const float* x      = (const float*)d_in[0];
  const float* conn   = (const float*)d_in[1];
  const int*   ei     = (const int*)d_in[2];
  const float* sqrtdg = (const float*)d_in[3];
  const float* qkv_w  = (const float*)d_in[4];
  const float* qkv_b  = (const float*)d_in[5];
  const float* w1     = (const float*)d_in[6];
  const float* b1     = (const float*)d_in[7];
  const float* wscore = (const float*)d_in[8];
  const float* w2     = (const float*)d_in[9];
  const float* b2     = (const float*)d_in[10];
  const float* bncg   = (const float*)d_in[11];
  const float* bncb   = (const float*)d_in[12];
  const float* degc   = (const float*)d_in[13];
  const float* f1w    = (const float*)d_in[14];
  const float* f1b    = (const float*)d_in[15];
  const float* f2w    = (const float*)d_in[16];
  const float* f2b    = (const float*)d_in[17];
  const float* bn1g   = (const float*)d_in[18];
  const float* bn1b   = (const float*)d_in[19];
  const float* bn2g   = (const float*)d_in[20];
  const float* bn2b   = (const float*)d_in[21];

  float* ws  = (float*)d_ws;
  int*   wsi = (int*)d_ws;
  float* outF = (float*)d_out;
  float* t_c2 = outF + N_NODES * 128;  // holds t, overwritten in place with c2
  unsigned short* w1bf = (unsigned short*)(wsi + OFF_WBF);
  unsigned short* w2bf = (unsigned short*)(wsi + OFF_WBF + 16384);

  (void)hipMemsetAsync(d_ws, 0, (size_t)ZERO_WORDS * 4, stream);

  k_cvt<<<dim3(128), dim3(256), 0, stream>>>(w1, w2, w1bf, w2bf);
  k_qkv<<<dim3(157), dim3(256), 0, stream>>>(x, qkv_w, qkv_b, ws + OFF_QKV);
  k_deg<<<dim3(625), dim3(256), 0, stream>>>(ei, wsi + OFF_DEG);
  k_edge<<<dim3(2500), dim3(256), 0, stream>>>(conn, ei, ws + OFF_QKV, w1bf, w2bf,
                                               b1, b2, wscore, t_c2,
                                               ws + OFF_ESC, ws + OFF_DEN,
                                               ws + OFF_SUMS);
  k_scan<<<dim3(1), dim3(1024), 0, stream>>>(wsi + OFF_DEG, wsi + OFF_ROWPTR,
                                             wsi + OFF_CURSOR);
  k_scatter<<<dim3(625), dim3(256), 0, stream>>>(ei, wsi + OFF_CURSOR, wsi + OFF_ELIST);
  k_bnfin<<<dim3(1), dim3(128), 0, stream>>>(ws + OFF_SUMS, bncg, bncb,
                                             1.f / N_EDGES, ws + OFF_SS);
  k_agg<<<dim3(1250), dim3(256), 0, stream>>>(wsi + OFF_ROWPTR, wsi + OFF_ELIST, ei,
                                              ws + OFF_ESC, ws + OFF_DEN, t_c2,
                                              ws + OFF_QKV, x, sqrtdg, degc,
                                              ws + OFF_SS, ws + OFF_HRES);
  k_colstats<<<dim3(40), dim3(256), 0, stream>>>(ws + OFF_HRES, N_NODES,
                                                 ws + OFF_SUMS + 256);
  k_bnfin<<<dim3(1), dim3(128), 0, stream>>>(ws + OFF_SUMS + 256, bn1g, bn1b,
                                             1.f / N_NODES, ws + OFF_SS + 256);
  k_ffn1<<<dim3(157), dim3(256), 0, stream>>>(ws + OFF_HRES, ws + OFF_SS + 256,
                                              f1w, f1b, ws + OFF_MID);
  k_ffn2<<<dim3(313), dim3(256), 0, stream>>>(ws + OFF_MID, f2w, f2b, ws + OFF_HRES,
                                              ws + OFF_Y);
  k_colstats<<<dim3(40), dim3(256), 0, stream>>>(ws + OFF_Y, N_NODES,
                                                 ws + OFF_SUMS + 512);
  k_bnfin<<<dim3(1), dim3(128), 0, stream>>>(ws + OFF_SUMS + 512, bn2g, bn2b,
                                             1.f / N_NODES, ws + OFF_SS + 512);
  k_bnapply<<<dim3(1250), dim3(256), 0, stream>>>(ws + OFF_Y, ws + OFF_SS + 512,
                                                  outF, N_NODES * 128 / 4, 0);
}

// Round 4
// 511.248 us; speedup vs baseline: 1.5141x; 1.1077x over previous
//
#include <hip/hip_runtime.h>
#include <math.h>

typedef float f4 __attribute__((ext_vector_type(4)));
typedef float f2 __attribute__((ext_vector_type(2)));
typedef short bf16x8 __attribute__((ext_vector_type(8)));
typedef float f32x4v __attribute__((ext_vector_type(4)));
typedef unsigned short u16x4 __attribute__((ext_vector_type(4)));

#define N_NODES 10000
#define N_EDGES 160000

// ---- workspace layout (units: 4-byte words) ----
#define OFF_DEN     0          // 80000 f32 (N*8) softmax denominators [zeroed]
#define OFF_SUMS    80000      // 768: bnc s/sq | bn1 s/sq | bn2 s/sq  [zeroed]
#define OFF_DEG     80768      // 10000 int degrees                    [zeroed]
#define ZERO_WORDS  90768
#define OFF_ROWPTR  90768      // 10001 int
#define OFF_CURSOR  100772     // 10000 int
#define OFF_ELIST   110772     // 160000 int
#define OFF_SS      270772     // 768: bnc scale/shift | bn1 | bn2
#define OFF_WBF     271544     // 81920 words = 163840 u16 bf16 weights
#define OFF_QKV     353464     // 3,840,000 f32 (N x 384)
#define OFF_ESC     4193464    // 1,280,000 f32 (E x 8) exp(score)
#define OFF_HRES    5473464    // 1,280,000 f32 (N x 128)
#define OFF_MID     6753464    // 2,560,000 f32 (N x 256) ffn mid
#define OFF_CONNB   9313464    // 10,240,000 words = E x 128 bf16 conn
// total 19,553,464 words = 78.2 MB

__device__ __forceinline__ unsigned short f2bf(float f) {
  unsigned int u = __float_as_uint(f);
  u = (u + 0x7fffu + ((u >> 16) & 1u)) >> 16;
  return (unsigned short)u;
}
__device__ __forceinline__ float bf2f(unsigned short p) {
  return __uint_as_float(((unsigned int)p) << 16);
}

// ---------------- prep: conn->bf16, all weights->bf16, deg ----------------
__global__ void k_prep(const float* __restrict__ conn, const float* __restrict__ w1,
                       const float* __restrict__ w2, const float* __restrict__ qw,
                       const float* __restrict__ f1w, const float* __restrict__ f2w,
                       const int* __restrict__ ei, unsigned short* __restrict__ connB,
                       unsigned short* __restrict__ wb16, int* __restrict__ deg) {
  int g = blockIdx.x * 256 + threadIdx.x;
  if (g < 2560000) {
    int i0 = g * 8;
    f4 a = *(const f4*)&conn[i0];
    f4 b = *(const f4*)&conn[i0 + 4];
    u16x4 pa = { f2bf(a[0]), f2bf(a[1]), f2bf(a[2]), f2bf(a[3]) };
    u16x4 pb = { f2bf(b[0]), f2bf(b[1]), f2bf(b[2]), f2bf(b[3]) };
    *(u16x4*)&connB[i0] = pa;
    *(u16x4*)&connB[i0 + 4] = pb;
  }
  if (g < 20480) {
    int i0 = g * 8;
    const float* src; unsigned short* dst; int off;
    if (i0 < 32768)       { src = w1;  dst = wb16;          off = i0; }
    else if (i0 < 49152)  { src = w2;  dst = wb16 + 32768;  off = i0 - 32768; }
    else if (i0 < 98304)  { src = qw;  dst = wb16 + 49152;  off = i0 - 49152; }
    else if (i0 < 131072) { src = f1w; dst = wb16 + 98304;  off = i0 - 98304; }
    else                  { src = f2w; dst = wb16 + 131072; off = i0 - 131072; }
    f4 a = *(const f4*)&src[off];
    f4 b = *(const f4*)&src[off + 4];
    u16x4 pa = { f2bf(a[0]), f2bf(a[1]), f2bf(a[2]), f2bf(a[3]) };
    u16x4 pb = { f2bf(b[0]), f2bf(b[1]), f2bf(b[2]), f2bf(b[3]) };
    *(u16x4*)&dst[off] = pa;
    *(u16x4*)&dst[off + 4] = pb;
  }
  if (g < N_EDGES) atomicAdd(&deg[ei[g]], 1);
}

// ---------------- fused edge kernel: 8 waves, 64 edges/block ----------------
// GEMM1 (LDS-free): wave w computes Ew/Eb col strip [w*16,w*16+16) from global
// bf16 conn + w1. Stage of qk=Q[dst]+K[src] overlaps GEMM1 (barrier after).
// epi1: c = relu(sign*sqrt(qk*Ew)+Eb) -> LDS (in place over qk); score reduce,
// exp+atomic den inline at lr==0. GEMM2: wave w rows (w&3)*16.., cols (w>>2)*64..
// epi2: t = acc+b2+connB -> global; BN-c stats.
__global__ __launch_bounds__(512, 6) void k_edge(
    const unsigned short* __restrict__ connB, const int* __restrict__ ei,
    const float* __restrict__ qkv, const unsigned short* __restrict__ w1bf,
    const unsigned short* __restrict__ w2bf, const float* __restrict__ b1,
    const float* __restrict__ b2, const float* __restrict__ wsc_g,
    float* __restrict__ t_out, float* __restrict__ escore,
    float* __restrict__ den, float* __restrict__ bnc_sums) {
  __shared__ unsigned short qkcBF[8192];  // 64x128 bf16 swizzled: qk then c
  __shared__ float csum[128], csq[128];
  const int tid = threadIdx.x;
  const int e0 = blockIdx.x * 64;
  if (tid < 128) csum[tid] = 0.f;
  else if (tid < 256) csq[tid - 128] = 0.f;

  // stage qk -> LDS (writes drain during GEMM1; barrier after GEMM1)
#pragma unroll
  for (int it = 0; it < 4; ++it) {
    int i = tid + it * 512;  // 2048 f4-chunks
    int row = i >> 5, kq = i & 31;
    int dst = ei[e0 + row], src = ei[N_EDGES + e0 + row];
    f4 qv = *(const f4*)&qkv[dst * 384 + kq * 4];
    f4 kv = *(const f4*)&qkv[src * 384 + 128 + kq * 4];
    f4 s = qv + kv;
    u16x4 sp = { f2bf(s[0]), f2bf(s[1]), f2bf(s[2]), f2bf(s[3]) };
    int wb = ((row * 256 + kq * 8) ^ ((row & 7) << 4)) >> 1;
    *(u16x4*)&qkcBF[wb] = sp;
  }

  const int w = tid >> 6;         // wave = head, 0..7
  const int lq = (tid >> 4) & 3;
  const int lr = tid & 15;

  // ---- GEMM1 (no LDS): Ew col strip + Eb col strip, acc 32 regs ----
  f32x4v accW[4] = {}, accB[4] = {};
#pragma unroll
  for (int ks = 0; ks < 4; ++ks) {
    bf16x8 bW = *(const bf16x8*)&w1bf[(w * 16 + lr) * 128 + ks * 32 + lq * 8];
    bf16x8 bB = *(const bf16x8*)&w1bf[(128 + w * 16 + lr) * 128 + ks * 32 + lq * 8];
#pragma unroll
    for (int rf = 0; rf < 4; ++rf) {
      bf16x8 a = *(const bf16x8*)&connB[(e0 + rf * 16 + lr) * 128 + ks * 32 + lq * 8];
      accW[rf] = __builtin_amdgcn_mfma_f32_16x16x32_bf16(a, bW, accW[rf], 0, 0, 0);
      accB[rf] = __builtin_amdgcn_mfma_f32_16x16x32_bf16(a, bB, accB[rf], 0, 0, 0);
    }
  }
  __syncthreads();  // qk stage complete

  // ---- epilogue 1 ----
  {
    const float wv = wsc_g[lr * 8 + w];
    const float bw = b1[w * 16 + lr];
    const float bb = b1[128 + w * 16 + lr];
#pragma unroll
    for (int rf = 0; rf < 4; ++rf) {
#pragma unroll
      for (int r = 0; r < 4; ++r) {
        int row = rf * 16 + lq * 4 + r;
        int qoff = ((row * 256 + (w * 16 + lr) * 2) ^ ((row & 7) << 4)) >> 1;
        float qk = bf2f(qkcBF[qoff]);
        float ew = accW[rf][r] + bw;
        float eb = accB[rf][r] + bb;
        float z = qk * ew;
        float cval = fmaxf(copysignf(sqrtf(fabsf(z)), z) + eb, 0.f);
        float sp = cval * wv;
        sp += __shfl_xor(sp, 1);
        sp += __shfl_xor(sp, 2);
        sp += __shfl_xor(sp, 4);
        sp += __shfl_xor(sp, 8);
        if (lr == 0) {
          float s = fminf(fmaxf(sp, -5.f), 5.f);
          float es = expf(s);
          escore[(e0 + row) * 8 + w] = es;
          atomicAdd(&den[ei[e0 + row] * 8 + w], es);
        }
        qkcBF[qoff] = f2bf(cval);  // c overwrites qk in place
      }
    }
  }
  __syncthreads();

  // ---- GEMM2: rows (w&3)*16.., cols (w>>2)*64.. ----
  const int r16 = (w & 3) * 16;
  const int cb = (w >> 2) * 64;
  f32x4v acc2[4] = {};
#pragma unroll
  for (int ks = 0; ks < 4; ++ks) {
    int row = r16 + lr;
    int off = ((row * 256 + ks * 64 + lq * 16) ^ ((row & 7) << 4)) >> 1;
    bf16x8 a = *(const bf16x8*)&qkcBF[off];
#pragma unroll
    for (int cf = 0; cf < 4; ++cf) {
      bf16x8 b = *(const bf16x8*)&w2bf[(cb + cf * 16 + lr) * 128 + ks * 32 + lq * 8];
      acc2[cf] = __builtin_amdgcn_mfma_f32_16x16x32_bf16(a, b, acc2[cf], 0, 0, 0);
    }
  }
  // ---- epilogue 2 ----
#pragma unroll
  for (int cf = 0; cf < 4; ++cf) {
    const int col = cb + cf * 16 + lr;
    const float bias = b2[col];
    float sp = 0.f, qp = 0.f;
#pragma unroll
    for (int r = 0; r < 4; ++r) {
      int row = r16 + lq * 4 + r;
      float cn = bf2f(connB[(e0 + row) * 128 + col]);
      float t = acc2[cf][r] + bias + cn;
      t_out[(e0 + row) * 128 + col] = t;
      sp += t;
      qp += t * t;
    }
    sp += __shfl_xor(sp, 16);
    sp += __shfl_xor(sp, 32);
    qp += __shfl_xor(qp, 16);
    qp += __shfl_xor(qp, 32);
    if (lq == 0) {
      atomicAdd(&csum[col], sp);
      atomicAdd(&csq[col], qp);
    }
  }
  __syncthreads();
  if (tid < 128) {
    atomicAdd(&bnc_sums[tid], csum[tid]);
    atomicAdd(&bnc_sums[128 + tid], csq[tid]);
  }
}

// ---------------- qkv = x @ qkv_w.T + qkv_b (MFMA, 32-row tiles) ----------------
__global__ __launch_bounds__(256, 6) void k_qkv(const float* __restrict__ x,
                                                const unsigned short* __restrict__ qwbf,
                                                const float* __restrict__ b,
                                                float* __restrict__ out) {
  __shared__ unsigned short xBF[4096];  // 32x128 bf16 swizzled
  const int tid = threadIdx.x;
  const int r0 = blockIdx.x * 32;
#pragma unroll
  for (int it = 0; it < 4; ++it) {
    int i = tid + it * 256;  // 1024 f4-chunks
    int row = i >> 5, kq = i & 31;
    int gr = r0 + row; if (gr > N_NODES - 1) gr = N_NODES - 1;
    f4 v = *(const f4*)&x[gr * 128 + kq * 4];
    u16x4 p = { f2bf(v[0]), f2bf(v[1]), f2bf(v[2]), f2bf(v[3]) };
    int wb = ((row * 256 + kq * 8) ^ ((row & 7) << 4)) >> 1;
    *(u16x4*)&xBF[wb] = p;
  }
  __syncthreads();
  const int w = tid >> 6, lq = (tid >> 4) & 3, lr = tid & 15;
  f32x4v acc[2][6] = {};
#pragma unroll
  for (int ks = 0; ks < 4; ++ks) {
    bf16x8 a0, a1;
    {
      int row = lr;
      a0 = *(const bf16x8*)&xBF[((row * 256 + ks * 64 + lq * 16) ^ ((row & 7) << 4)) >> 1];
      row = 16 + lr;
      a1 = *(const bf16x8*)&xBF[((row * 256 + ks * 64 + lq * 16) ^ ((row & 7) << 4)) >> 1];
    }
#pragma unroll
    for (int cf = 0; cf < 6; ++cf) {
      bf16x8 bv = *(const bf16x8*)&qwbf[(w * 96 + cf * 16 + lr) * 128 + ks * 32 + lq * 8];
      acc[0][cf] = __builtin_amdgcn_mfma_f32_16x16x32_bf16(a0, bv, acc[0][cf], 0, 0, 0);
      acc[1][cf] = __builtin_amdgcn_mfma_f32_16x16x32_bf16(a1, bv, acc[1][cf], 0, 0, 0);
    }
  }
#pragma unroll
  for (int rf = 0; rf < 2; ++rf) {
#pragma unroll
    for (int cf = 0; cf < 6; ++cf) {
      int col = w * 96 + cf * 16 + lr;
      float bias = b[col];
#pragma unroll
      for (int r = 0; r < 4; ++r) {
        int gr = r0 + rf * 16 + lq * 4 + r;
        if (gr < N_NODES) out[gr * 384 + col] = acc[rf][cf][r] + bias;
      }
    }
  }
}

// ---------------- scan (block 0) + bnc finalize (block 1) ----------------
__global__ __launch_bounds__(1024) void k_scanfin(
    const int* __restrict__ deg, int* __restrict__ rowptr, int* __restrict__ cursor,
    const float* __restrict__ sums, const float* __restrict__ g,
    const float* __restrict__ bta, float* __restrict__ ss) {
  if (blockIdx.x == 1) {
    int c = threadIdx.x;
    if (c < 128) {
      float inv_n = 1.f / N_EDGES;
      float mu = sums[c] * inv_n;
      float var = sums[128 + c] * inv_n - mu * mu;
      float sc = g[c] / sqrtf(var + 1e-5f);
      ss[c] = sc;
      ss[128 + c] = bta[c] - mu * sc;
    }
    return;
  }
  __shared__ int wsum[16];
  const int t = threadIdx.x;
  const int base = t * 10;
  int d[10];
  int s0 = 0;
#pragma unroll
  for (int i = 0; i < 10; ++i) {
    int idx = base + i;
    d[i] = (idx < N_NODES) ? deg[idx] : 0;
    s0 += d[i];
  }
  int s = s0;
  const int lane = t & 63;
#pragma unroll
  for (int o = 1; o < 64; o <<= 1) {
    int v = __shfl_up(s, o);
    if (lane >= o) s += v;
  }
  if (lane == 63) wsum[t >> 6] = s;
  __syncthreads();
  if (t < 16) {
    int v = wsum[t];
#pragma unroll
    for (int o = 1; o < 16; o <<= 1) {
      int u = __shfl_up(v, o);
      if (t >= o) v += u;
    }
    wsum[t] = v;
  }
  __syncthreads();
  int incl = s + ((t >= 64) ? wsum[(t >> 6) - 1] : 0);
  int run = incl - s0;
#pragma unroll
  for (int i = 0; i < 10; ++i) {
    int idx = base + i;
    if (idx < N_NODES) {
      rowptr[idx] = run;
      cursor[idx] = run;
      run += d[i];
    }
  }
  if (t == 1023) rowptr[N_NODES] = incl;
}

__global__ void k_scatter(const int* __restrict__ ei, int* __restrict__ cursor,
                          int* __restrict__ elist) {
  int e = blockIdx.x * 256 + threadIdx.x;
  if (e < N_EDGES) {
    int pos = atomicAdd(&cursor[ei[e]], 1);
    elist[pos] = e;
  }
}

__global__ void k_bnfin(const float* __restrict__ sums, const float* __restrict__ g,
                        const float* __restrict__ bta, float inv_n,
                        float* __restrict__ ss) {
  int c = threadIdx.x;  // 128
  float mu = sums[c] * inv_n;
  float var = sums[128 + c] * inv_n - mu * mu;
  float sc = g[c] / sqrtf(var + 1e-5f);
  ss[c] = sc;
  ss[128 + c] = bta[c] - mu * sc;
}

// ---------------- aggregation + bn1 stats inline ----------------
__global__ __launch_bounds__(256) void k_agg(
    const int* __restrict__ rowptr, const int* __restrict__ elist,
    const int* __restrict__ ei, const float* __restrict__ escore,
    const float* __restrict__ den, float* __restrict__ t_c2,
    const float* __restrict__ qkv, const float* __restrict__ x,
    const float* __restrict__ sqrtdeg, const float* __restrict__ degc,
    const float* __restrict__ ss, float* __restrict__ hres,
    float* __restrict__ bn1_sums) {
  __shared__ float csum[128], csq[128];
  const int tid = threadIdx.x;
  if (tid < 128) csum[tid] = 0.f;
  else csq[tid - 128] = 0.f;
  __syncthreads();
  const int sl = tid & 31;
  const int n = blockIdx.x * 8 + (tid >> 5);
  const int c0 = sl * 4;
  const int head = sl >> 2;
  const int st = rowptr[n], en = rowptr[n + 1];
  const float invd = 1.f / (den[n * 8 + head] + 1e-16f);
  const f4 sc = *(const f4*)&ss[c0];
  const f4 sh = *(const f4*)&ss[128 + c0];
  f4 acc = {};
  int e = (st < en) ? elist[st] : 0;
  for (int idx = st; idx < en; ++idx) {
    const int ec = e;
    if (idx + 1 < en) e = elist[idx + 1];
    const float al = escore[ec * 8 + head] * invd;
    const int src = ei[N_EDGES + ec];
    f4 tv = *(const f4*)&t_c2[ec * 128 + c0];
    f4 vv = *(const f4*)&qkv[src * 384 + 256 + c0];
    f4 c2v = tv * sc + sh;
#pragma unroll
    for (int t = 0; t < 4; ++t) c2v[t] = fmaxf(c2v[t], 0.f);
    *(f4*)&t_c2[ec * 128 + c0] = c2v;  // final c2 (each edge once)
    acc += al * (c2v + vv);
  }
  const float sd = sqrtdeg[n];
  f4 d0 = { degc[c0 * 2], degc[c0 * 2 + 2], degc[c0 * 2 + 4], degc[c0 * 2 + 6] };
  f4 d1 = { degc[c0 * 2 + 1], degc[c0 * 2 + 3], degc[c0 * 2 + 5], degc[c0 * 2 + 7] };
  f4 xr = *(const f4*)&x[n * 128 + c0];
  f4 hr = acc * (d0 + sd * d1) + xr;
  *(f4*)&hres[n * 128 + c0] = hr;
#pragma unroll
  for (int t = 0; t < 4; ++t) {
    atomicAdd(&csum[c0 + t], hr[t]);
    atomicAdd(&csq[c0 + t], hr[t] * hr[t]);
  }
  __syncthreads();
  if (tid < 128) {
    atomicAdd(&bn1_sums[tid], csum[tid]);
    atomicAdd(&bn1_sums[128 + tid], csq[tid]);
  }
}

// ---------------- ffn1: mid = relu(bn1(hres) @ f1w.T + f1b) ----------------
__global__ __launch_bounds__(256, 6) void k_ffn1(const float* __restrict__ hres,
                                                 const float* __restrict__ ss,
                                                 const unsigned short* __restrict__ wbf,
                                                 const float* __restrict__ b,
                                                 float* __restrict__ mid) {
  __shared__ unsigned short aBF[4096];  // 32x128
  const int tid = threadIdx.x;
  const int r0 = blockIdx.x * 32;
#pragma unroll
  for (int it = 0; it < 4; ++it) {
    int i = tid + it * 256;
    int row = i >> 5, kq = i & 31;
    int gr = r0 + row; if (gr > N_NODES - 1) gr = N_NODES - 1;
    f4 v = *(const f4*)&hres[gr * 128 + kq * 4];
    f4 sc = *(const f4*)&ss[kq * 4];
    f4 sh = *(const f4*)&ss[128 + kq * 4];
    v = v * sc + sh;
    u16x4 p = { f2bf(v[0]), f2bf(v[1]), f2bf(v[2]), f2bf(v[3]) };
    int wb = ((row * 256 + kq * 8) ^ ((row & 7) << 4)) >> 1;
    *(u16x4*)&aBF[wb] = p;
  }
  __syncthreads();
  const int w = tid >> 6, lq = (tid >> 4) & 3, lr = tid & 15;
  f32x4v acc[2][4] = {};
#pragma unroll
  for (int ks = 0; ks < 4; ++ks) {
    bf16x8 a0, a1;
    {
      int row = lr;
      a0 = *(const bf16x8*)&aBF[((row * 256 + ks * 64 + lq * 16) ^ ((row & 7) << 4)) >> 1];
      row = 16 + lr;
      a1 = *(const bf16x8*)&aBF[((row * 256 + ks * 64 + lq * 16) ^ ((row & 7) << 4)) >> 1];
    }
#pragma unroll
    for (int cf = 0; cf < 4; ++cf) {
      bf16x8 bv = *(const bf16x8*)&wbf[(w * 64 + cf * 16 + lr) * 128 + ks * 32 + lq * 8];
      acc[0][cf] = __builtin_amdgcn_mfma_f32_16x16x32_bf16(a0, bv, acc[0][cf], 0, 0, 0);
      acc[1][cf] = __builtin_amdgcn_mfma_f32_16x16x32_bf16(a1, bv, acc[1][cf], 0, 0, 0);
    }
  }
#pragma unroll
  for (int rf = 0; rf < 2; ++rf) {
#pragma unroll
    for (int cf = 0; cf < 4; ++cf) {
      int col = w * 64 + cf * 16 + lr;
      float bias = b[col];
#pragma unroll
      for (int r = 0; r < 4; ++r) {
        int gr = r0 + rf * 16 + lq * 4 + r;
        if (gr < N_NODES) mid[gr * 256 + col] = fmaxf(acc[rf][cf][r] + bias, 0.f);
      }
    }
  }
}

// ---------------- ffn2: y = mid @ f2w.T + f2b + hres, bn2 stats inline ----------------
__global__ __launch_bounds__(256, 6) void k_ffn2(const float* __restrict__ mid,
                                                 const unsigned short* __restrict__ wbf,
                                                 const float* __restrict__ b,
                                                 const float* __restrict__ hres,
                                                 float* __restrict__ y,
                                                 float* __restrict__ bn2_sums) {
  __shared__ unsigned short aBF[8192];  // 32x256, row stride 512B
  __shared__ float csum[128], csq[128];
  const int tid = threadIdx.x;
  const int r0 = blockIdx.x * 32;
  if (tid < 128) csum[tid] = 0.f;
  else csq[tid - 128] = 0.f;
#pragma unroll
  for (int it = 0; it < 8; ++it) {
    int i = tid + it * 256;  // 2048 f4-chunks
    int row = i >> 6, kq = i & 63;
    int gr = r0 + row; if (gr > N_NODES - 1) gr = N_NODES - 1;
    f4 v = *(const f4*)&mid[gr * 256 + kq * 4];
    u16x4 p = { f2bf(v[0]), f2bf(v[1]), f2bf(v[2]), f2bf(v[3]) };
    int wb = ((row * 512 + kq * 8) ^ ((row & 7) << 4)) >> 1;
    *(u16x4*)&aBF[wb] = p;
  }
  __syncthreads();
  const int w = tid >> 6, lq = (tid >> 4) & 3, lr = tid & 15;
  f32x4v acc[2][2] = {};
#pragma unroll
  for (int ks = 0; ks < 8; ++ks) {
    bf16x8 a0, a1;
    {
      int row = lr;
      a0 = *(const bf16x8*)&aBF[((row * 512 + ks * 64 + lq * 16) ^ ((row & 7) << 4)) >> 1];
      row = 16 + lr;
      a1 = *(const bf16x8*)&aBF[((row * 512 + ks * 64 + lq * 16) ^ ((row & 7) << 4)) >> 1];
    }
#pragma unroll
    for (int cf = 0; cf < 2; ++cf) {
      bf16x8 bv = *(const bf16x8*)&wbf[(w * 32 + cf * 16 + lr) * 256 + ks * 32 + lq * 8];
      acc[0][cf] = __builtin_amdgcn_mfma_f32_16x16x32_bf16(a0, bv, acc[0][cf], 0, 0, 0);
      acc[1][cf] = __builtin_amdgcn_mfma_f32_16x16x32_bf16(a1, bv, acc[1][cf], 0, 0, 0);
    }
  }
#pragma unroll
  for (int rf = 0; rf < 2; ++rf) {
#pragma unroll
    for (int cf = 0; cf < 2; ++cf) {
      int col = w * 32 + cf * 16 + lr;
      float bias = b[col];
      float sp = 0.f, qp = 0.f;
#pragma unroll
      for (int r = 0; r < 4; ++r) {
        int gr = r0 + rf * 16 + lq * 4 + r;
        if (gr < N_NODES) {
          float o = acc[rf][cf][r] + bias + hres[gr * 128 + col];
          y[gr * 128 + col] = o;
          sp += o;
          qp += o * o;
        }
      }
      atomicAdd(&csum[col], sp);
      atomicAdd(&csq[col], qp);
    }
  }
  __syncthreads();
  if (tid < 128) {
    atomicAdd(&bn2_sums[tid], csum[tid]);
    atomicAdd(&bn2_sums[128 + tid], csq[tid]);
  }
}

// ---------------- final BN apply (in place on out) ----------------
__global__ void k_bnfinal(float* __restrict__ yio, const float* __restrict__ ss) {
  int i = blockIdx.x * 256 + threadIdx.x;
  if (i < N_NODES * 32) {
    int c = (i & 31) * 4;
    f4 v = *(const f4*)&yio[i * 4];
    f4 sc = *(const f4*)&ss[c];
    f4 sh = *(const f4*)&ss[128 + c];
    v = v * sc + sh;
    *(f4*)&yio[i * 4] = v;
  }
}

extern "C" void kernel_launch(void* const* d_in, const int* in_sizes, int n_in,
                              void* d_out, int out_size, void* d_ws, size_t ws_size,
                              hipStream_t stream) {
  const float* x      = (const float*)d_in[0];
  const float* conn   = (const float*)d_in[1];
  const int*   ei     = (const int*)d_in[2];
  const float* sqrtdg = (const float*)d_in[3];
  const float* qkv_w  = (const float*)d_in[4];
  const float* qkv_b  = (const float*)d_in[5];
  const float* w1     = (const float*)d_in[6];
  const float* b1     = (const float*)d_in[7];
  const float* wscore = (const float*)d_in[8];
  const float* w2     = (const float*)d_in[9];
  const float* b2     = (const float*)d_in[10];
  const float* bncg   = (const float*)d_in[11];
  const float* bncb   = (const float*)d_in[12];
  const float* degc   = (const float*)d_in[13];
  const float* f1w    = (const float*)d_in[14];
  const float* f1b    = (const float*)d_in[15];
  const float* f2w    = (const float*)d_in[16];
  const float* f2b    = (const float*)d_in[17];
  const float* bn1g   = (const float*)d_in[18];
  const float* bn1b   = (const float*)d_in[19];
  const float* bn2g   = (const float*)d_in[20];
  const float* bn2b   = (const float*)d_in[21];

  float* ws  = (float*)d_ws;
  int*   wsi = (int*)d_ws;
  float* outF = (float*)d_out;
  float* t_c2 = outF + N_NODES * 128;
  unsigned short* connB = (unsigned short*)(wsi + OFF_CONNB);
  unsigned short* wb16  = (unsigned short*)(wsi + OFF_WBF);
  unsigned short* w1bf  = wb16;
  unsigned short* w2bf  = wb16 + 32768;
  unsigned short* qwbf  = wb16 + 49152;
  unsigned short* f1wbf = wb16 + 98304;
  unsigned short* f2wbf = wb16 + 131072;

  (void)hipMemsetAsync(d_ws, 0, (size_t)ZERO_WORDS * 4, stream);

  k_prep<<<dim3(10000), dim3(256), 0, stream>>>(conn, w1, w2, qkv_w, f1w, f2w, ei,
                                                connB, wb16, wsi + OFF_DEG);
  k_qkv<<<dim3(313), dim3(256), 0, stream>>>(x, qwbf, qkv_b, ws + OFF_QKV);
  k_edge<<<dim3(2500), dim3(512), 0, stream>>>(connB, ei, ws + OFF_QKV, w1bf, w2bf,
                                               b1, b2, wscore, t_c2,
                                               ws + OFF_ESC, ws + OFF_DEN,
                                               ws + OFF_SUMS);
  k_scanfin<<<dim3(2), dim3(1024), 0, stream>>>(wsi + OFF_DEG, wsi + OFF_ROWPTR,
                                                wsi + OFF_CURSOR, ws + OFF_SUMS,
                                                bncg, bncb, ws + OFF_SS);
  k_scatter<<<dim3(625), dim3(256), 0, stream>>>(ei, wsi + OFF_CURSOR, wsi + OFF_ELIST);
  k_agg<<<dim3(1250), dim3(256), 0, stream>>>(wsi + OFF_ROWPTR, wsi + OFF_ELIST, ei,
                                              ws + OFF_ESC, ws + OFF_DEN, t_c2,
                                              ws + OFF_QKV, x, sqrtdg, degc,
                                              ws + OFF_SS, ws + OFF_HRES,
                                              ws + OFF_SUMS + 256);
  k_bnfin<<<dim3(1), dim3(128), 0, stream>>>(ws + OFF_SUMS + 256, bn1g, bn1b,
                                             1.f / N_NODES, ws + OFF_SS + 256);
  k_ffn1<<<dim3(313), dim3(256), 0, stream>>>(ws + OFF_HRES, ws + OFF_SS + 256,
                                              f1wbf, f1b, ws + OFF_MID);
  k_ffn2<<<dim3(313), dim3(256), 0, stream>>>(ws + OFF_MID, f2wbf, f2b, ws + OFF_HRES,
                                              outF, ws + OFF_SUMS + 512);
  k_bnfin<<<dim3(1), dim3(128), 0, stream>>>(ws + OFF_SUMS + 512, bn2g, bn2b,
                                             1.f / N_NODES, ws + OFF_SS + 512);
  k_bnfinal<<<dim3(1250), dim3(256), 0, stream>>>(outF, ws + OFF_SS + 512);
}

// Round 5
// 463.415 us; speedup vs baseline: 1.6704x; 1.1032x over previous
//
#include <hip/hip_runtime.h>
#include <math.h>

typedef float f4 __attribute__((ext_vector_type(4)));
typedef float f2 __attribute__((ext_vector_type(2)));
typedef short bf16x8 __attribute__((ext_vector_type(8)));
typedef float f32x4v __attribute__((ext_vector_type(4)));
typedef unsigned short u16x4 __attribute__((ext_vector_type(4)));

#define N_NODES 10000
#define N_EDGES 160000

// ---- workspace layout (units: 4-byte words) ----
#define OFF_DEN     0          // 80000 f32 (N*8) softmax denominators [zeroed]
#define OFF_SUMS    80000      // 768: bnc s/sq | bn1 s/sq | bn2 s/sq  [zeroed]
#define OFF_DEG     80768      // 10000 int degrees                    [zeroed]
#define ZERO_WORDS  90768
#define OFF_ROWPTR  90768      // 10001 int
#define OFF_CURSOR  100772     // 10000 int
#define OFF_ELIST   110772     // 160000 int
#define OFF_SS      270772     // 768: bnc scale/shift | bn1 | bn2
#define OFF_WBF     271544     // 81920 words = 163840 u16 bf16 weights
#define OFF_QKV     353464     // 3,840,000 f32 (N x 384)
#define OFF_ESC     4193464    // 1,280,000 f32 (E x 8) exp(score)
#define OFF_HRES    5473464    // 1,280,000 f32 (N x 128)
#define OFF_MID     6753464    // 2,560,000 f32 (N x 256) ffn mid
// total ~37 MB

__device__ __forceinline__ unsigned short f2bf(float f) {
  unsigned int u = __float_as_uint(f);
  u = (u + 0x7fffu + ((u >> 16) & 1u)) >> 16;
  return (unsigned short)u;
}
__device__ __forceinline__ float bf2f(unsigned short p) {
  return __uint_as_float(((unsigned int)p) << 16);
}

// ---------------- prep: weights->bf16, deg ----------------
__global__ void k_prep(const float* __restrict__ w1, const float* __restrict__ w2,
                       const float* __restrict__ qw, const float* __restrict__ f1w,
                       const float* __restrict__ f2w, const int* __restrict__ ei,
                       unsigned short* __restrict__ wb16, int* __restrict__ deg) {
  int g = blockIdx.x * 256 + threadIdx.x;
  if (g < 20480) {
    int i0 = g * 8;
    const float* src; unsigned short* dst; int off;
    if (i0 < 32768)       { src = w1;  dst = wb16;          off = i0; }
    else if (i0 < 49152)  { src = w2;  dst = wb16 + 32768;  off = i0 - 32768; }
    else if (i0 < 98304)  { src = qw;  dst = wb16 + 49152;  off = i0 - 49152; }
    else if (i0 < 131072) { src = f1w; dst = wb16 + 98304;  off = i0 - 98304; }
    else                  { src = f2w; dst = wb16 + 131072; off = i0 - 131072; }
    f4 a = *(const f4*)&src[off];
    f4 b = *(const f4*)&src[off + 4];
    u16x4 pa = { f2bf(a[0]), f2bf(a[1]), f2bf(a[2]), f2bf(a[3]) };
    u16x4 pb = { f2bf(b[0]), f2bf(b[1]), f2bf(b[2]), f2bf(b[3]) };
    *(u16x4*)&dst[off] = pa;
    *(u16x4*)&dst[off + 4] = pb;
  }
  if (g < N_EDGES) atomicAdd(&deg[ei[g]], 1);
}

// ---------------- fused edge kernel: 8 waves, 64 edges/block ----------------
// stage: conn + qk=Q[dst]+K[src] -> bf16 LDS (XOR-swizzled), coalesced f4 reads.
// GEMM1: wave w = head w computes Ew/Eb col strip [w*16,w*16+16); A from LDS.
// epi1 : c = relu(sign*sqrt(qk*Ew)+Eb) -> LDS in place over qk; score
//        shfl-reduce; exp+clip+atomic den at lr==0.
// GEMM2: wave w rows (w&3)*16.., cols (w>>2)*64..; A from LDS.
// epi2 : t = acc + b2 + conn(LDS) -> global; BN-c stats block-reduce.
__global__ __launch_bounds__(512, 6) void k_edge(
    const float* __restrict__ conn, const int* __restrict__ ei,
    const float* __restrict__ qkv, const unsigned short* __restrict__ w1bf,
    const unsigned short* __restrict__ w2bf, const float* __restrict__ b1,
    const float* __restrict__ b2, const float* __restrict__ wsc_g,
    float* __restrict__ t_out, float* __restrict__ escore,
    float* __restrict__ den, float* __restrict__ bnc_sums) {
  __shared__ unsigned short connBF[8192];  // 64x128 bf16, XOR-swizzled
  __shared__ unsigned short qkcBF[8192];   // qk, overwritten by c in epi1
  __shared__ float csum[128], csq[128];
  const int tid = threadIdx.x;
  const int e0 = blockIdx.x * 64;
  if (tid < 128) csum[tid] = 0.f;
  else if (tid < 256) csq[tid - 128] = 0.f;

  // stage conn + qk (4 iterations each, 512 threads cover 2048 f4-chunks)
#pragma unroll
  for (int it = 0; it < 4; ++it) {
    int i = tid + it * 512;
    int row = i >> 5, kq = i & 31;
    int wb = ((row * 256 + kq * 8) ^ ((row & 7) << 4)) >> 1;  // u16 index
    f4 cv = *(const f4*)&conn[(e0 + row) * 128 + kq * 4];
    u16x4 cp = { f2bf(cv[0]), f2bf(cv[1]), f2bf(cv[2]), f2bf(cv[3]) };
    *(u16x4*)&connBF[wb] = cp;
    int dst = ei[e0 + row], src = ei[N_EDGES + e0 + row];
    f4 qv = *(const f4*)&qkv[dst * 384 + kq * 4];
    f4 kv = *(const f4*)&qkv[src * 384 + 128 + kq * 4];
    f4 s = qv + kv;
    u16x4 sp = { f2bf(s[0]), f2bf(s[1]), f2bf(s[2]), f2bf(s[3]) };
    *(u16x4*)&qkcBF[wb] = sp;
  }
  __syncthreads();

  const int w = tid >> 6;         // wave = head, 0..7
  const int lq = (tid >> 4) & 3;
  const int lr = tid & 15;

  // ---- GEMM1: Ew col strip + Eb col strip (A from LDS, 32 acc regs) ----
  f32x4v accW[4] = {}, accB[4] = {};
#pragma unroll
  for (int ks = 0; ks < 4; ++ks) {
    bf16x8 bW = *(const bf16x8*)&w1bf[(w * 16 + lr) * 128 + ks * 32 + lq * 8];
    bf16x8 bB = *(const bf16x8*)&w1bf[(128 + w * 16 + lr) * 128 + ks * 32 + lq * 8];
#pragma unroll
    for (int rf = 0; rf < 4; ++rf) {
      int row = rf * 16 + lr;
      int off = ((row * 256 + ks * 64 + lq * 16) ^ ((row & 7) << 4)) >> 1;
      bf16x8 a = *(const bf16x8*)&connBF[off];
      accW[rf] = __builtin_amdgcn_mfma_f32_16x16x32_bf16(a, bW, accW[rf], 0, 0, 0);
      accB[rf] = __builtin_amdgcn_mfma_f32_16x16x32_bf16(a, bB, accB[rf], 0, 0, 0);
    }
  }

  // ---- epilogue 1 ----
  {
    const float wv = wsc_g[lr * 8 + w];
    const float bw = b1[w * 16 + lr];
    const float bb = b1[128 + w * 16 + lr];
#pragma unroll
    for (int rf = 0; rf < 4; ++rf) {
#pragma unroll
      for (int r = 0; r < 4; ++r) {
        int row = rf * 16 + lq * 4 + r;
        int qoff = ((row * 256 + (w * 16 + lr) * 2) ^ ((row & 7) << 4)) >> 1;
        float qk = bf2f(qkcBF[qoff]);
        float ew = accW[rf][r] + bw;
        float eb = accB[rf][r] + bb;
        float z = qk * ew;
        float cval = fmaxf(copysignf(sqrtf(fabsf(z)), z) + eb, 0.f);
        float sp = cval * wv;
        sp += __shfl_xor(sp, 1);
        sp += __shfl_xor(sp, 2);
        sp += __shfl_xor(sp, 4);
        sp += __shfl_xor(sp, 8);
        if (lr == 0) {
          float s = fminf(fmaxf(sp, -5.f), 5.f);
          float es = expf(s);
          escore[(e0 + row) * 8 + w] = es;
          atomicAdd(&den[ei[e0 + row] * 8 + w], es);
        }
        qkcBF[qoff] = f2bf(cval);  // c overwrites qk in place
      }
    }
  }
  __syncthreads();

  // ---- GEMM2: rows (w&3)*16.., cols (w>>2)*64.. ----
  const int r16 = (w & 3) * 16;
  const int cb = (w >> 2) * 64;
  f32x4v acc2[4] = {};
#pragma unroll
  for (int ks = 0; ks < 4; ++ks) {
    int row = r16 + lr;
    int off = ((row * 256 + ks * 64 + lq * 16) ^ ((row & 7) << 4)) >> 1;
    bf16x8 a = *(const bf16x8*)&qkcBF[off];
#pragma unroll
    for (int cf = 0; cf < 4; ++cf) {
      bf16x8 b = *(const bf16x8*)&w2bf[(cb + cf * 16 + lr) * 128 + ks * 32 + lq * 8];
      acc2[cf] = __builtin_amdgcn_mfma_f32_16x16x32_bf16(a, b, acc2[cf], 0, 0, 0);
    }
  }
  // ---- epilogue 2: t = acc + b2 + conn(LDS) ----
#pragma unroll
  for (int cf = 0; cf < 4; ++cf) {
    const int col = cb + cf * 16 + lr;
    const float bias = b2[col];
    float sp = 0.f, qp = 0.f;
#pragma unroll
    for (int r = 0; r < 4; ++r) {
      int row = r16 + lq * 4 + r;
      int coff = ((row * 256 + col * 2) ^ ((row & 7) << 4)) >> 1;
      float cn = bf2f(connBF[coff]);
      float t = acc2[cf][r] + bias + cn;
      t_out[(e0 + row) * 128 + col] = t;
      sp += t;
      qp += t * t;
    }
    sp += __shfl_xor(sp, 16);
    sp += __shfl_xor(sp, 32);
    qp += __shfl_xor(qp, 16);
    qp += __shfl_xor(qp, 32);
    if (lq == 0) {
      atomicAdd(&csum[col], sp);
      atomicAdd(&csq[col], qp);
    }
  }
  __syncthreads();
  if (tid < 128) {
    atomicAdd(&bnc_sums[tid], csum[tid]);
    atomicAdd(&bnc_sums[128 + tid], csq[tid]);
  }
}

// ---------------- qkv = x @ qkv_w.T + qkv_b (MFMA, 32-row tiles) ----------------
__global__ __launch_bounds__(256, 6) void k_qkv(const float* __restrict__ x,
                                                const unsigned short* __restrict__ qwbf,
                                                const float* __restrict__ b,
                                                float* __restrict__ out) {
  __shared__ unsigned short xBF[4096];  // 32x128 bf16 swizzled
  const int tid = threadIdx.x;
  const int r0 = blockIdx.x * 32;
#pragma unroll
  for (int it = 0; it < 4; ++it) {
    int i = tid + it * 256;  // 1024 f4-chunks
    int row = i >> 5, kq = i & 31;
    int gr = r0 + row; if (gr > N_NODES - 1) gr = N_NODES - 1;
    f4 v = *(const f4*)&x[gr * 128 + kq * 4];
    u16x4 p = { f2bf(v[0]), f2bf(v[1]), f2bf(v[2]), f2bf(v[3]) };
    int wb = ((row * 256 + kq * 8) ^ ((row & 7) << 4)) >> 1;
    *(u16x4*)&xBF[wb] = p;
  }
  __syncthreads();
  const int w = tid >> 6, lq = (tid >> 4) & 3, lr = tid & 15;
  f32x4v acc[2][6] = {};
#pragma unroll
  for (int ks = 0; ks < 4; ++ks) {
    bf16x8 a0, a1;
    {
      int row = lr;
      a0 = *(const bf16x8*)&xBF[((row * 256 + ks * 64 + lq * 16) ^ ((row & 7) << 4)) >> 1];
      row = 16 + lr;
      a1 = *(const bf16x8*)&xBF[((row * 256 + ks * 64 + lq * 16) ^ ((row & 7) << 4)) >> 1];
    }
#pragma unroll
    for (int cf = 0; cf < 6; ++cf) {
      bf16x8 bv = *(const bf16x8*)&qwbf[(w * 96 + cf * 16 + lr) * 128 + ks * 32 + lq * 8];
      acc[0][cf] = __builtin_amdgcn_mfma_f32_16x16x32_bf16(a0, bv, acc[0][cf], 0, 0, 0);
      acc[1][cf] = __builtin_amdgcn_mfma_f32_16x16x32_bf16(a1, bv, acc[1][cf], 0, 0, 0);
    }
  }
#pragma unroll
  for (int rf = 0; rf < 2; ++rf) {
#pragma unroll
    for (int cf = 0; cf < 6; ++cf) {
      int col = w * 96 + cf * 16 + lr;
      float bias = b[col];
#pragma unroll
      for (int r = 0; r < 4; ++r) {
        int gr = r0 + rf * 16 + lq * 4 + r;
        if (gr < N_NODES) out[gr * 384 + col] = acc[rf][cf][r] + bias;
      }
    }
  }
}

// ---------------- scan (block 0) + bnc finalize (block 1) ----------------
__global__ __launch_bounds__(1024) void k_scanfin(
    const int* __restrict__ deg, int* __restrict__ rowptr, int* __restrict__ cursor,
    const float* __restrict__ sums, const float* __restrict__ g,
    const float* __restrict__ bta, float* __restrict__ ss) {
  if (blockIdx.x == 1) {
    int c = threadIdx.x;
    if (c < 128) {
      float inv_n = 1.f / N_EDGES;
      float mu = sums[c] * inv_n;
      float var = sums[128 + c] * inv_n - mu * mu;
      float sc = g[c] / sqrtf(var + 1e-5f);
      ss[c] = sc;
      ss[128 + c] = bta[c] - mu * sc;
    }
    return;
  }
  __shared__ int wsum[16];
  const int t = threadIdx.x;
  const int base = t * 10;
  int d[10];
  int s0 = 0;
#pragma unroll
  for (int i = 0; i < 10; ++i) {
    int idx = base + i;
    d[i] = (idx < N_NODES) ? deg[idx] : 0;
    s0 += d[i];
  }
  int s = s0;
  const int lane = t & 63;
#pragma unroll
  for (int o = 1; o < 64; o <<= 1) {
    int v = __shfl_up(s, o);
    if (lane >= o) s += v;
  }
  if (lane == 63) wsum[t >> 6] = s;
  __syncthreads();
  if (t < 16) {
    int v = wsum[t];
#pragma unroll
    for (int o = 1; o < 16; o <<= 1) {
      int u = __shfl_up(v, o);
      if (t >= o) v += u;
    }
    wsum[t] = v;
  }
  __syncthreads();
  int incl = s + ((t >= 64) ? wsum[(t >> 6) - 1] : 0);
  int run = incl - s0;
#pragma unroll
  for (int i = 0; i < 10; ++i) {
    int idx = base + i;
    if (idx < N_NODES) {
      rowptr[idx] = run;
      cursor[idx] = run;
      run += d[i];
    }
  }
  if (t == 1023) rowptr[N_NODES] = incl;
}

__global__ void k_scatter(const int* __restrict__ ei, int* __restrict__ cursor,
                          int* __restrict__ elist) {
  int e = blockIdx.x * 256 + threadIdx.x;
  if (e < N_EDGES) {
    int pos = atomicAdd(&cursor[ei[e]], 1);
    elist[pos] = e;
  }
}

__global__ void k_bnfin(const float* __restrict__ sums, const float* __restrict__ g,
                        const float* __restrict__ bta, float inv_n,
                        float* __restrict__ ss) {
  int c = threadIdx.x;  // 128
  float mu = sums[c] * inv_n;
  float var = sums[128 + c] * inv_n - mu * mu;
  float sc = g[c] / sqrtf(var + 1e-5f);
  ss[c] = sc;
  ss[128 + c] = bta[c] - mu * sc;
}

// ---------------- aggregation + bn1 stats inline ----------------
__global__ __launch_bounds__(256) void k_agg(
    const int* __restrict__ rowptr, const int* __restrict__ elist,
    const int* __restrict__ ei, const float* __restrict__ escore,
    const float* __restrict__ den, float* __restrict__ t_c2,
    const float* __restrict__ qkv, const float* __restrict__ x,
    const float* __restrict__ sqrtdeg, const float* __restrict__ degc,
    const float* __restrict__ ss, float* __restrict__ hres,
    float* __restrict__ bn1_sums) {
  __shared__ float csum[128], csq[128];
  const int tid = threadIdx.x;
  if (tid < 128) csum[tid] = 0.f;
  else csq[tid - 128] = 0.f;
  __syncthreads();
  const int sl = tid & 31;
  const int n = blockIdx.x * 8 + (tid >> 5);
  const int c0 = sl * 4;
  const int head = sl >> 2;
  const int st = rowptr[n], en = rowptr[n + 1];
  const float invd = 1.f / (den[n * 8 + head] + 1e-16f);
  const f4 sc = *(const f4*)&ss[c0];
  const f4 sh = *(const f4*)&ss[128 + c0];
  f4 acc = {};
  int e = (st < en) ? elist[st] : 0;
  for (int idx = st; idx < en; ++idx) {
    const int ec = e;
    if (idx + 1 < en) e = elist[idx + 1];
    const float al = escore[ec * 8 + head] * invd;
    const int src = ei[N_EDGES + ec];
    f4 tv = *(const f4*)&t_c2[ec * 128 + c0];
    f4 vv = *(const f4*)&qkv[src * 384 + 256 + c0];
    f4 c2v = tv * sc + sh;
#pragma unroll
    for (int t = 0; t < 4; ++t) c2v[t] = fmaxf(c2v[t], 0.f);
    *(f4*)&t_c2[ec * 128 + c0] = c2v;  // final c2 (each edge once)
    acc += al * (c2v + vv);
  }
  const float sd = sqrtdeg[n];
  f4 d0 = { degc[c0 * 2], degc[c0 * 2 + 2], degc[c0 * 2 + 4], degc[c0 * 2 + 6] };
  f4 d1 = { degc[c0 * 2 + 1], degc[c0 * 2 + 3], degc[c0 * 2 + 5], degc[c0 * 2 + 7] };
  f4 xr = *(const f4*)&x[n * 128 + c0];
  f4 hr = acc * (d0 + sd * d1) + xr;
  *(f4*)&hres[n * 128 + c0] = hr;
#pragma unroll
  for (int t = 0; t < 4; ++t) {
    atomicAdd(&csum[c0 + t], hr[t]);
    atomicAdd(&csq[c0 + t], hr[t] * hr[t]);
  }
  __syncthreads();
  if (tid < 128) {
    atomicAdd(&bn1_sums[tid], csum[tid]);
    atomicAdd(&bn1_sums[128 + tid], csq[tid]);
  }
}

// ---------------- ffn1: mid = relu(bn1(hres) @ f1w.T + f1b) ----------------
__global__ __launch_bounds__(256, 6) void k_ffn1(const float* __restrict__ hres,
                                                 const float* __restrict__ ss,
                                                 const unsigned short* __restrict__ wbf,
                                                 const float* __restrict__ b,
                                                 float* __restrict__ mid) {
  __shared__ unsigned short aBF[4096];  // 32x128
  const int tid = threadIdx.x;
  const int r0 = blockIdx.x * 32;
#pragma unroll
  for (int it = 0; it < 4; ++it) {
    int i = tid + it * 256;
    int row = i >> 5, kq = i & 31;
    int gr = r0 + row; if (gr > N_NODES - 1) gr = N_NODES - 1;
    f4 v = *(const f4*)&hres[gr * 128 + kq * 4];
    f4 sc = *(const f4*)&ss[kq * 4];
    f4 sh = *(const f4*)&ss[128 + kq * 4];
    v = v * sc + sh;
    u16x4 p = { f2bf(v[0]), f2bf(v[1]), f2bf(v[2]), f2bf(v[3]) };
    int wb = ((row * 256 + kq * 8) ^ ((row & 7) << 4)) >> 1;
    *(u16x4*)&aBF[wb] = p;
  }
  __syncthreads();
  const int w = tid >> 6, lq = (tid >> 4) & 3, lr = tid & 15;
  f32x4v acc[2][4] = {};
#pragma unroll
  for (int ks = 0; ks < 4; ++ks) {
    bf16x8 a0, a1;
    {
      int row = lr;
      a0 = *(const bf16x8*)&aBF[((row * 256 + ks * 64 + lq * 16) ^ ((row & 7) << 4)) >> 1];
      row = 16 + lr;
      a1 = *(const bf16x8*)&aBF[((row * 256 + ks * 64 + lq * 16) ^ ((row & 7) << 4)) >> 1];
    }
#pragma unroll
    for (int cf = 0; cf < 4; ++cf) {
      bf16x8 bv = *(const bf16x8*)&wbf[(w * 64 + cf * 16 + lr) * 128 + ks * 32 + lq * 8];
      acc[0][cf] = __builtin_amdgcn_mfma_f32_16x16x32_bf16(a0, bv, acc[0][cf], 0, 0, 0);
      acc[1][cf] = __builtin_amdgcn_mfma_f32_16x16x32_bf16(a1, bv, acc[1][cf], 0, 0, 0);
    }
  }
#pragma unroll
  for (int rf = 0; rf < 2; ++rf) {
#pragma unroll
    for (int cf = 0; cf < 4; ++cf) {
      int col = w * 64 + cf * 16 + lr;
      float bias = b[col];
#pragma unroll
      for (int r = 0; r < 4; ++r) {
        int gr = r0 + rf * 16 + lq * 4 + r;
        if (gr < N_NODES) mid[gr * 256 + col] = fmaxf(acc[rf][cf][r] + bias, 0.f);
      }
    }
  }
}

// ---------------- ffn2: y = mid @ f2w.T + f2b + hres, bn2 stats inline ----------------
__global__ __launch_bounds__(256, 6) void k_ffn2(const float* __restrict__ mid,
                                                 const unsigned short* __restrict__ wbf,
                                                 const float* __restrict__ b,
                                                 const float* __restrict__ hres,
                                                 float* __restrict__ y,
                                                 float* __restrict__ bn2_sums) {
  __shared__ unsigned short aBF[8192];  // 32x256, row stride 512B
  __shared__ float csum[128], csq[128];
  const int tid = threadIdx.x;
  const int r0 = blockIdx.x * 32;
  if (tid < 128) csum[tid] = 0.f;
  else csq[tid - 128] = 0.f;
#pragma unroll
  for (int it = 0; it < 8; ++it) {
    int i = tid + it * 256;  // 2048 f4-chunks
    int row = i >> 6, kq = i & 63;
    int gr = r0 + row; if (gr > N_NODES - 1) gr = N_NODES - 1;
    f4 v = *(const f4*)&mid[gr * 256 + kq * 4];
    u16x4 p = { f2bf(v[0]), f2bf(v[1]), f2bf(v[2]), f2bf(v[3]) };
    int wb = ((row * 512 + kq * 8) ^ ((row & 7) << 4)) >> 1;
    *(u16x4*)&aBF[wb] = p;
  }
  __syncthreads();
  const int w = tid >> 6, lq = (tid >> 4) & 3, lr = tid & 15;
  f32x4v acc[2][2] = {};
#pragma unroll
  for (int ks = 0; ks < 8; ++ks) {
    bf16x8 a0, a1;
    {
      int row = lr;
      a0 = *(const bf16x8*)&aBF[((row * 512 + ks * 64 + lq * 16) ^ ((row & 7) << 4)) >> 1];
      row = 16 + lr;
      a1 = *(const bf16x8*)&aBF[((row * 512 + ks * 64 + lq * 16) ^ ((row & 7) << 4)) >> 1];
    }
#pragma unroll
    for (int cf = 0; cf < 2; ++cf) {
      bf16x8 bv = *(const bf16x8*)&wbf[(w * 32 + cf * 16 + lr) * 256 + ks * 32 + lq * 8];
      acc[0][cf] = __builtin_amdgcn_mfma_f32_16x16x32_bf16(a0, bv, acc[0][cf], 0, 0, 0);
      acc[1][cf] = __builtin_amdgcn_mfma_f32_16x16x32_bf16(a1, bv, acc[1][cf], 0, 0, 0);
    }
  }
#pragma unroll
  for (int rf = 0; rf < 2; ++rf) {
#pragma unroll
    for (int cf = 0; cf < 2; ++cf) {
      int col = w * 32 + cf * 16 + lr;
      float bias = b[col];
      float sp = 0.f, qp = 0.f;
#pragma unroll
      for (int r = 0; r < 4; ++r) {
        int gr = r0 + rf * 16 + lq * 4 + r;
        if (gr < N_NODES) {
          float o = acc[rf][cf][r] + bias + hres[gr * 128 + col];
          y[gr * 128 + col] = o;
          sp += o;
          qp += o * o;
        }
      }
      atomicAdd(&csum[col], sp);
      atomicAdd(&csq[col], qp);
    }
  }
  __syncthreads();
  if (tid < 128) {
    atomicAdd(&bn2_sums[tid], csum[tid]);
    atomicAdd(&bn2_sums[128 + tid], csq[tid]);
  }
}

// ---------------- final BN apply (in place on out) ----------------
__global__ void k_bnfinal(float* __restrict__ yio, const float* __restrict__ ss) {
  int i = blockIdx.x * 256 + threadIdx.x;
  if (i < N_NODES * 32) {
    int c = (i & 31) * 4;
    f4 v = *(const f4*)&yio[i * 4];
    f4 sc = *(const f4*)&ss[c];
    f4 sh = *(const f4*)&ss[128 + c];
    v = v * sc + sh;
    *(f4*)&yio[i * 4] = v;
  }
}

extern "C" void kernel_launch(void* const* d_in, const int* in_sizes, int n_in,
                              void* d_out, int out_size, void* d_ws, size_t ws_size,
                              hipStream_t stream) {
  const float* x      = (const float*)d_in[0];
  const float* conn   = (const float*)d_in[1];
  const int*   ei     = (const int*)d_in[2];
  const float* sqrtdg = (const float*)d_in[3];
  const float* qkv_w  = (const float*)d_in[4];
  const float* qkv_b  = (const float*)d_in[5];
  const float* w1     = (const float*)d_in[6];
  const float* b1     = (const float*)d_in[7];
  const float* wscore = (const float*)d_in[8];
  const float* w2     = (const float*)d_in[9];
  const float* b2     = (const float*)d_in[10];
  const float* bncg   = (const float*)d_in[11];
  const float* bncb   = (const float*)d_in[12];
  const float* degc   = (const float*)d_in[13];
  const float* f1w    = (const float*)d_in[14];
  const float* f1b    = (const float*)d_in[15];
  const float* f2w    = (const float*)d_in[16];
  const float* f2b    = (const float*)d_in[17];
  const float* bn1g   = (const float*)d_in[18];
  const float* bn1b   = (const float*)d_in[19];
  const float* bn2g   = (const float*)d_in[20];
  const float* bn2b   = (const float*)d_in[21];

  float* ws  = (float*)d_ws;
  int*   wsi = (int*)d_ws;
  float* outF = (float*)d_out;
  float* t_c2 = outF + N_NODES * 128;
  unsigned short* wb16  = (unsigned short*)(wsi + OFF_WBF);
  unsigned short* w1bf  = wb16;
  unsigned short* w2bf  = wb16 + 32768;
  unsigned short* qwbf  = wb16 + 49152;
  unsigned short* f1wbf = wb16 + 98304;
  unsigned short* f2wbf = wb16 + 131072;

  (void)hipMemsetAsync(d_ws, 0, (size_t)ZERO_WORDS * 4, stream);

  k_prep<<<dim3(625), dim3(256), 0, stream>>>(w1, w2, qkv_w, f1w, f2w, ei,
                                              wb16, wsi + OFF_DEG);
  k_qkv<<<dim3(313), dim3(256), 0, stream>>>(x, qwbf, qkv_b, ws + OFF_QKV);
  k_edge<<<dim3(2500), dim3(512), 0, stream>>>(conn, ei, ws + OFF_QKV, w1bf, w2bf,
                                               b1, b2, wscore, t_c2,
                                               ws + OFF_ESC, ws + OFF_DEN,
                                               ws + OFF_SUMS);
  k_scanfin<<<dim3(2), dim3(1024), 0, stream>>>(wsi + OFF_DEG, wsi + OFF_ROWPTR,
                                                wsi + OFF_CURSOR, ws + OFF_SUMS,
                                                bncg, bncb, ws + OFF_SS);
  k_scatter<<<dim3(625), dim3(256), 0, stream>>>(ei, wsi + OFF_CURSOR, wsi + OFF_ELIST);
  k_agg<<<dim3(1250), dim3(256), 0, stream>>>(wsi + OFF_ROWPTR, wsi + OFF_ELIST, ei,
                                              ws + OFF_ESC, ws + OFF_DEN, t_c2,
                                              ws + OFF_QKV, x, sqrtdg, degc,
                                              ws + OFF_SS, ws + OFF_HRES,
                                              ws + OFF_SUMS + 256);
  k_bnfin<<<dim3(1), dim3(128), 0, stream>>>(ws + OFF_SUMS + 256, bn1g, bn1b,
                                             1.f / N_NODES, ws + OFF_SS + 256);
  k_ffn1<<<dim3(313), dim3(256), 0, stream>>>(ws + OFF_HRES, ws + OFF_SS + 256,
                                              f1wbf, f1b, ws + OFF_MID);
  k_ffn2<<<dim3(313), dim3(256), 0, stream>>>(ws + OFF_MID, f2wbf, f2b, ws + OFF_HRES,
                                              outF, ws + OFF_SUMS + 512);
  k_bnfin<<<dim3(1), dim3(128), 0, stream>>>(ws + OFF_SUMS + 512, bn2g, bn2b,
                                             1.f / N_NODES, ws + OFF_SS + 512);
  k_bnfinal<<<dim3(1250), dim3(256), 0, stream>>>(outF, ws + OFF_SS + 512);
}